// Round 2
// baseline (2055.135 us; speedup 1.0000x reference)
//
#include <hip/hip_runtime.h>
#include <hip/hip_bf16.h>

// ---- problem constants ----
#define ZX_LD   4384   // in_proj output width (z 2048 | xBC 2304 | dt 32)
#define XC_LD   2304   // conv dim (x 2048 | B 128 | C 128)
#define NH      32
#define HD      64
#define DS      128
#define CHK     256
#define NC      16
#define LTOT    4096
#define ROWS    8192   // BATCH * SEQLEN
#define DSSM    2048

// =====================================================================
// GEMM: C[m][n] = sum_k A[m][k] * B[n][k]   (row-major, strided)
// 128x128 tile, BK=16, 256 threads, 8x8 per thread (split 4+4 mapping)
// =====================================================================
__global__ __launch_bounds__(256) void gemm_bt_f32(
    const float* __restrict__ A, const float* __restrict__ B,
    float* __restrict__ C, int M, int N, int K,
    int lda, int ldb, int ldc)
{
  __shared__ float As[16][132];   // [k][m], padded
  __shared__ float Bs[16][132];   // [k][n], padded
  const int bm = blockIdx.y * 128;
  const int bn = blockIdx.x * 128;
  const int tid = threadIdx.x;
  const int tx = tid & 15;        // n-dir
  const int ty = tid >> 4;        // m-dir
  const int lr = tid >> 1;        // 0..127 row of tile for loads
  const int lc = (tid & 1) * 8;   // k offset 0/8

  const float* Ap = A + (size_t)(bm + lr) * lda + lc;
  const int brow = bn + lr;
  const float* Bp = B + (size_t)brow * ldb + lc;
  const bool bok = brow < N;

  float acc[8][8];
#pragma unroll
  for (int i = 0; i < 8; ++i)
#pragma unroll
    for (int j = 0; j < 8; ++j) acc[i][j] = 0.f;

  for (int k0 = 0; k0 < K; k0 += 16) {
    float4 a0 = *(const float4*)(Ap + k0);
    float4 a1 = *(const float4*)(Ap + k0 + 4);
    float4 b0 = make_float4(0.f, 0.f, 0.f, 0.f);
    float4 b1 = make_float4(0.f, 0.f, 0.f, 0.f);
    if (bok) { b0 = *(const float4*)(Bp + k0); b1 = *(const float4*)(Bp + k0 + 4); }
    __syncthreads();
    As[lc+0][lr]=a0.x; As[lc+1][lr]=a0.y; As[lc+2][lr]=a0.z; As[lc+3][lr]=a0.w;
    As[lc+4][lr]=a1.x; As[lc+5][lr]=a1.y; As[lc+6][lr]=a1.z; As[lc+7][lr]=a1.w;
    Bs[lc+0][lr]=b0.x; Bs[lc+1][lr]=b0.y; Bs[lc+2][lr]=b0.z; Bs[lc+3][lr]=b0.w;
    Bs[lc+4][lr]=b1.x; Bs[lc+5][lr]=b1.y; Bs[lc+6][lr]=b1.z; Bs[lc+7][lr]=b1.w;
    __syncthreads();
#pragma unroll
    for (int kk = 0; kk < 16; ++kk) {
      float4 A0 = *(const float4*)&As[kk][ty*4];
      float4 A1 = *(const float4*)&As[kk][64 + ty*4];
      float4 B0 = *(const float4*)&Bs[kk][tx*4];
      float4 B1 = *(const float4*)&Bs[kk][64 + tx*4];
      float am[8] = {A0.x,A0.y,A0.z,A0.w,A1.x,A1.y,A1.z,A1.w};
      float bv[8] = {B0.x,B0.y,B0.z,B0.w,B1.x,B1.y,B1.z,B1.w};
#pragma unroll
      for (int i = 0; i < 8; ++i)
#pragma unroll
        for (int j = 0; j < 8; ++j) acc[i][j] = fmaf(am[i], bv[j], acc[i][j]);
    }
  }
#pragma unroll
  for (int i = 0; i < 8; ++i) {
    const int m = bm + ((i < 4) ? (ty*4 + i) : (64 + ty*4 + i - 4));
#pragma unroll
    for (int j = 0; j < 8; ++j) {
      const int n = bn + ((j < 4) ? (tx*4 + j) : (64 + tx*4 + j - 4));
      if (n < N) C[(size_t)m * ldc + n] = acc[i][j];
    }
  }
}

// =====================================================================
// depthwise causal conv (k=4) + bias + SiLU over xBC columns of zx
// =====================================================================
__global__ __launch_bounds__(256) void conv_silu_kernel(
    const float* __restrict__ zx, const float* __restrict__ cw,
    const float* __restrict__ cb, float* __restrict__ xconv)
{
  const int ch  = blockIdx.x * 256 + threadIdx.x;  // 0..2303
  const int row = blockIdx.y;                      // 0..8191
  const int l   = row & (LTOT - 1);
  float acc = cb[ch];
#pragma unroll
  for (int k = 0; k < 4; ++k) {
    const int ls = l - 3 + k;
    if (ls >= 0) acc = fmaf(zx[(size_t)(row - 3 + k) * ZX_LD + 2048 + ch], cw[ch*4 + k], acc);
  }
  const float r = acc / (1.f + __expf(-acc));   // silu
  xconv[(size_t)row * XC_LD + ch] = r;
}

// =====================================================================
// dt = softplus(dt_raw + dt_bias)
// =====================================================================
__global__ __launch_bounds__(256) void dt_kernel(
    const float* __restrict__ zx, const float* __restrict__ dtb,
    float* __restrict__ dtv)
{
  const int idx = blockIdx.x * 256 + threadIdx.x;  // < ROWS*NH
  const int row = idx >> 5;
  const int hh  = idx & 31;
  const float x = zx[(size_t)row * ZX_LD + 4352 + hh] + dtb[hh];
  dtv[idx] = (x > 20.f) ? x : log1pf(__expf(x));
}

// =====================================================================
// per (b,c,h): cumsum(dA) within chunk; chunk totals; chunk states
// states[p][n] = sum_l B[l,n] * exp(Acs[255]-Acs[l]) * dt[l] * x[l,p]
// =====================================================================
__global__ __launch_bounds__(256) void chunk_states_kernel(
    const float* __restrict__ dtv, const float* __restrict__ A_log,
    const float* __restrict__ xconv,
    float* __restrict__ acs, float* __restrict__ totals,
    float* __restrict__ states)
{
  const int bid = blockIdx.x;          // ((b*16+c)*32+h)
  const int h = bid & 31;
  const int c = (bid >> 5) & 15;
  const int b = bid >> 9;
  const int rowbase = b * LTOT + c * CHK;
  const int l = threadIdx.x;

  __shared__ float sWdt[256];
  __shared__ float wsum[4];
  __shared__ float xw[64][68];     // [l][p] : x*dt*decay
  __shared__ float Bsh[64][132];   // [l][n]

  const float dt = dtv[(size_t)(rowbase + l) * NH + h];
  const float Ah = -__expf(A_log[h]);
  float v = dt * Ah;
  // inclusive block scan (wave scan + wave offsets)
#pragma unroll
  for (int off = 1; off < 64; off <<= 1) {
    float up = __shfl_up(v, off, 64);
    if ((l & 63) >= off) v += up;
  }
  if ((l & 63) == 63) wsum[l >> 6] = v;
  __syncthreads();
  const float w0 = wsum[0], w1 = wsum[1], w2 = wsum[2], w3 = wsum[3];
  const int wid = l >> 6;
  float base = 0.f;
  if (wid > 0) base += w0;
  if (wid > 1) base += w1;
  if (wid > 2) base += w2;
  const float acsl  = v + base;
  const float total = w0 + w1 + w2 + w3;
  acs[bid * 256 + l] = acsl;
  if (l == 0) totals[(b * 32 + h) * 16 + c] = total;
  sWdt[l] = __expf(total - acsl) * dt;   // consumed after next barrier

  const int tx = l & 15;   // n-dir
  const int ty = l >> 4;   // p-dir
  const int r  = l >> 2;   // staging row
  float acc[4][8];
#pragma unroll
  for (int i = 0; i < 4; ++i)
#pragma unroll
    for (int j = 0; j < 8; ++j) acc[i][j] = 0.f;

  for (int ls = 0; ls < 4; ++ls) {
    const int l0 = ls * 64;
    __syncthreads();
    {
      const float wgt = sWdt[l0 + r];
      const float* xrow = xconv + (size_t)(rowbase + l0 + r) * XC_LD + h * HD + (l & 3) * 16;
      float* xd = &xw[r][(l & 3) * 16];
#pragma unroll
      for (int o = 0; o < 16; o += 4) {
        float4 t = *(const float4*)(xrow + o);
        xd[o+0] = t.x * wgt; xd[o+1] = t.y * wgt; xd[o+2] = t.z * wgt; xd[o+3] = t.w * wgt;
      }
      const float* br = xconv + (size_t)(rowbase + l0 + r) * XC_LD + 2048 + (l & 3) * 32;
      float* bd = &Bsh[r][(l & 3) * 32];
#pragma unroll
      for (int o = 0; o < 32; o += 4) {
        *(float4*)(bd + o) = *(const float4*)(br + o);
      }
    }
    __syncthreads();
#pragma unroll 8
    for (int s = 0; s < 64; ++s) {
      float4 pa = *(const float4*)&xw[s][ty*4];
      float4 b0 = *(const float4*)&Bsh[s][tx*4];
      float4 b1 = *(const float4*)&Bsh[s][64 + tx*4];
      float am[4] = {pa.x, pa.y, pa.z, pa.w};
      float bb[8] = {b0.x,b0.y,b0.z,b0.w,b1.x,b1.y,b1.z,b1.w};
#pragma unroll
      for (int i = 0; i < 4; ++i)
#pragma unroll
        for (int j = 0; j < 8; ++j) acc[i][j] = fmaf(am[i], bb[j], acc[i][j]);
    }
  }
  const size_t sbase = (size_t)bid * (HD * DS);
#pragma unroll
  for (int i = 0; i < 4; ++i) {
    const int p = ty * 4 + i;
#pragma unroll
    for (int j = 0; j < 8; ++j) {
      const int n = (j < 4) ? (tx*4 + j) : (64 + tx*4 + (j - 4));
      states[sbase + p * DS + n] = acc[i][j];
    }
  }
}

// =====================================================================
// inter-chunk scan per (b,h), IN PLACE:  st[c] <- P_c  (prev state), with
// P_{c+1} = exp(total_c)*P_c + states_c.  Each thread owns fixed elements.
// =====================================================================
__global__ __launch_bounds__(256) void chunk_prefix_kernel(
    float* __restrict__ st, const float* __restrict__ totals)
{
  const int bh = blockIdx.x;   // b*32+h
  const int b = bh >> 5;
  const int h = bh & 31;
  const int tid = threadIdx.x;
  float P[32];
#pragma unroll
  for (int e = 0; e < 32; ++e) P[e] = 0.f;
  for (int c = 0; c < NC; ++c) {
    const size_t base = (size_t)((b * 16 + c) * 32 + h) * (HD * DS);
    const float g = __expf(totals[bh * 16 + c]);
#pragma unroll
    for (int e = 0; e < 32; ++e) {
      const size_t idx = base + e * 256 + tid;
      const float s = st[idx];      // states_c (read BEFORE overwrite)
      st[idx] = P[e];               // prev_states for chunk c
      P[e] = fmaf(P[e], g, s);
    }
  }
}

// =====================================================================
// Y kernel per (b,c,h,l-tile): Y[l,p] = exp(Acs[l]) * C[l]·P[p]
//   + sum_{s<=l} exp(Acs[l]-Acs[s]) * (C[l]·B[s]) * dt[s] * x[s,p]
//   + x[l,p]*D[h]     -> ypre (strided overlay, leading dim ypld)
// =====================================================================
__global__ __launch_bounds__(256) void y_kernel(
    const float* __restrict__ xconv, const float* __restrict__ dtv,
    const float* __restrict__ acs,   const float* __restrict__ prevst,
    const float* __restrict__ Dv,    float* __restrict__ ypre, int ypld)
{
  const int bid = blockIdx.x;            // (((b*16+c)*32+h)*4+lt)
  const int lt = bid & 3;
  const int h  = (bid >> 2) & 31;
  const int c  = (bid >> 7) & 15;
  const int b  = bid >> 11;
  const int bch = (b * 16 + c) * 32 + h;
  const int rowbase = b * LTOT + c * CHK;
  const int tid = threadIdx.x;
  const int tx = tid & 15;
  const int ty = tid >> 4;
  const int r  = tid >> 2;
  const int q8 = (tid & 3) * 8;

  __shared__ float sAcs[256];
  __shared__ float sDt[256];
  __shared__ float Cst[32][68];   // [nn][l]
  __shared__ float Bst[32][68];   // [nn][s or p]
  __shared__ float Sst[64][68];   // [s][l] weighted scores
  __shared__ float xs[64][68];    // [s][p]

  sAcs[tid] = acs[bch * 256 + tid];
  sDt[tid]  = dtv[(size_t)(rowbase + tid) * NH + h];

  float yacc[4][4];
#pragma unroll
  for (int i = 0; i < 4; ++i)
#pragma unroll
    for (int j = 0; j < 4; ++j) yacc[i][j] = 0.f;

  // ---- phase 1: Y_off = (C @ P^T), scaled by exp(Acs[l]) afterwards ----
  for (int n0 = 0; n0 < DS; n0 += 32) {
    __syncthreads();
    {
      const float* crow = xconv + (size_t)(rowbase + lt*64 + r) * XC_LD + 2176 + n0 + q8;
      float4 c0 = *(const float4*)(crow);
      float4 c1 = *(const float4*)(crow + 4);
      Cst[q8+0][r]=c0.x; Cst[q8+1][r]=c0.y; Cst[q8+2][r]=c0.z; Cst[q8+3][r]=c0.w;
      Cst[q8+4][r]=c1.x; Cst[q8+5][r]=c1.y; Cst[q8+6][r]=c1.z; Cst[q8+7][r]=c1.w;
      const float* prow = prevst + (size_t)bch * (HD * DS) + r * DS + n0 + q8;
      float4 p0 = *(const float4*)(prow);
      float4 p1 = *(const float4*)(prow + 4);
      Bst[q8+0][r]=p0.x; Bst[q8+1][r]=p0.y; Bst[q8+2][r]=p0.z; Bst[q8+3][r]=p0.w;
      Bst[q8+4][r]=p1.x; Bst[q8+5][r]=p1.y; Bst[q8+6][r]=p1.z; Bst[q8+7][r]=p1.w;
    }
    __syncthreads();
#pragma unroll 8
    for (int nn = 0; nn < 32; ++nn) {
      float4 ca = *(const float4*)&Cst[nn][ty*4];
      float4 pb = *(const float4*)&Bst[nn][tx*4];
      float am[4] = {ca.x, ca.y, ca.z, ca.w};
      float bb[4] = {pb.x, pb.y, pb.z, pb.w};
#pragma unroll
      for (int i = 0; i < 4; ++i)
#pragma unroll
        for (int j = 0; j < 4; ++j) yacc[i][j] = fmaf(am[i], bb[j], yacc[i][j]);
    }
  }
#pragma unroll
  for (int i = 0; i < 4; ++i) {
    const float e = __expf(sAcs[lt*64 + ty*4 + i]);
#pragma unroll
    for (int j = 0; j < 4; ++j) yacc[i][j] *= e;
  }

  // ---- phase 2: causal diagonal tiles ----
  for (int st = 0; st <= lt; ++st) {
    float sacc[4][4];
#pragma unroll
    for (int i = 0; i < 4; ++i)
#pragma unroll
      for (int j = 0; j < 4; ++j) sacc[i][j] = 0.f;

    for (int n0 = 0; n0 < DS; n0 += 32) {
      __syncthreads();
      {
        const float* crow = xconv + (size_t)(rowbase + lt*64 + r) * XC_LD + 2176 + n0 + q8;
        float4 c0 = *(const float4*)(crow);
        float4 c1 = *(const float4*)(crow + 4);
        Cst[q8+0][r]=c0.x; Cst[q8+1][r]=c0.y; Cst[q8+2][r]=c0.z; Cst[q8+3][r]=c0.w;
        Cst[q8+4][r]=c1.x; Cst[q8+5][r]=c1.y; Cst[q8+6][r]=c1.z; Cst[q8+7][r]=c1.w;
        const float* brow = xconv + (size_t)(rowbase + st*64 + r) * XC_LD + 2048 + n0 + q8;
        float4 b0 = *(const float4*)(brow);
        float4 b1 = *(const float4*)(brow + 4);
        Bst[q8+0][r]=b0.x; Bst[q8+1][r]=b0.y; Bst[q8+2][r]=b0.z; Bst[q8+3][r]=b0.w;
        Bst[q8+4][r]=b1.x; Bst[q8+5][r]=b1.y; Bst[q8+6][r]=b1.z; Bst[q8+7][r]=b1.w;
      }
      __syncthreads();
#pragma unroll 8
      for (int nn = 0; nn < 32; ++nn) {
        float4 ca = *(const float4*)&Cst[nn][ty*4];
        float4 bb4 = *(const float4*)&Bst[nn][tx*4];
        float am[4] = {ca.x, ca.y, ca.z, ca.w};
        float bb[4] = {bb4.x, bb4.y, bb4.z, bb4.w};
#pragma unroll
        for (int i = 0; i < 4; ++i)
#pragma unroll
          for (int j = 0; j < 4; ++j) sacc[i][j] = fmaf(am[i], bb[j], sacc[i][j]);
      }
    }
    __syncthreads();  // done reading Cst/Bst; prior GEMM2 done reading Sst/xs
    // apply tril mask * exp(Acs[l]-Acs[s]) * dt[s]; store transposed [s][l]
#pragma unroll
    for (int j = 0; j < 4; ++j) {
      const int sj = st*64 + tx*4 + j;
      const float dts = sDt[sj];
      const float as  = sAcs[sj];
#pragma unroll
      for (int i = 0; i < 4; ++i) {
        const int li = lt*64 + ty*4 + i;
        float wv = 0.f;
        if (li >= sj) wv = sacc[i][j] * __expf(sAcs[li] - as) * dts;
        Sst[tx*4 + j][ty*4 + i] = wv;
      }
    }
    // stage xs[s][p]
    {
      const int q16 = (tid & 3) * 16;
      const float* xrow = xconv + (size_t)(rowbase + st*64 + r) * XC_LD + h * HD + q16;
#pragma unroll
      for (int o = 0; o < 16; o += 4) {
        *(float4*)&xs[r][q16 + o] = *(const float4*)(xrow + o);
      }
    }
    __syncthreads();
#pragma unroll 8
    for (int s = 0; s < 64; ++s) {
      float4 wv4 = *(const float4*)&Sst[s][ty*4];
      float4 xv4 = *(const float4*)&xs[s][tx*4];
      float am[4] = {wv4.x, wv4.y, wv4.z, wv4.w};
      float bb[4] = {xv4.x, xv4.y, xv4.z, xv4.w};
#pragma unroll
      for (int i = 0; i < 4; ++i)
#pragma unroll
        for (int j = 0; j < 4; ++j) yacc[i][j] = fmaf(am[i], bb[j], yacc[i][j]);
    }
  }

  // ---- epilogue: + x*D, write ypre (strided) ----
  const float Dh = Dv[h];
#pragma unroll
  for (int i = 0; i < 4; ++i) {
    const int row = rowbase + lt*64 + ty*4 + i;
    const float4 xv = *(const float4*)(xconv + (size_t)row * XC_LD + h * HD + tx*4);
    float* yr = ypre + (size_t)row * ypld + h * HD + tx*4;
    yr[0] = yacc[i][0] + xv.x * Dh;
    yr[1] = yacc[i][1] + xv.y * Dh;
    yr[2] = yacc[i][2] + xv.z * Dh;
    yr[3] = yacc[i][3] + xv.w * Dh;
  }
}

// =====================================================================
// gated RMSNorm, in place on the ypre overlay inside zx:
//   y = y*silu(z); y *= rsqrt(mean(y^2)+eps)*w
//   z = zx[row][0..2047], y = zx[row][2048..4095]
// =====================================================================
__global__ __launch_bounds__(256) void rmsnorm_gate_kernel(
    float* __restrict__ zx, const float* __restrict__ normw)
{
  const int row = blockIdx.x;
  const int tid = threadIdx.x;
  float vals[8];
  float ss = 0.f;
#pragma unroll
  for (int e = 0; e < 8; ++e) {
    const int col = e * 256 + tid;
    const float y = zx[(size_t)row * ZX_LD + 2048 + col];
    const float z = zx[(size_t)row * ZX_LD + col];
    const float sz = z / (1.f + __expf(-z));
    const float v = y * sz;
    vals[e] = v;
    ss += v * v;
  }
#pragma unroll
  for (int off = 32; off >= 1; off >>= 1) ss += __shfl_xor(ss, off, 64);
  __shared__ float red[4];
  if ((tid & 63) == 0) red[tid >> 6] = ss;
  __syncthreads();
  const float tot = red[0] + red[1] + red[2] + red[3];
  const float scale = rsqrtf(tot / (float)DSSM + 1e-5f);
#pragma unroll
  for (int e = 0; e < 8; ++e) {
    const int col = e * 256 + tid;
    zx[(size_t)row * ZX_LD + 2048 + col] = vals[e] * scale * normw[col];
  }
}

// =====================================================================
extern "C" void kernel_launch(void* const* d_in, const int* in_sizes, int n_in,
                              void* d_out, int out_size, void* d_ws, size_t ws_size,
                              hipStream_t stream)
{
  const float* u       = (const float*)d_in[0];
  const float* W_in    = (const float*)d_in[1];
  const float* conv_w  = (const float*)d_in[2];
  const float* conv_b  = (const float*)d_in[3];
  const float* dt_bias = (const float*)d_in[4];
  const float* A_log   = (const float*)d_in[5];
  const float* Dv      = (const float*)d_in[6];
  const float* norm_w  = (const float*)d_in[7];
  const float* W_out   = (const float*)d_in[8];
  float* out = (float*)d_out;

  // workspace layout (floats) — 63,702,016 floats = 243 MiB
  const size_t N_ZX  = (size_t)ROWS * ZX_LD;     // 35,913,728
  const size_t N_XC  = (size_t)ROWS * XC_LD;     // 18,874,368
  const size_t N_DT  = (size_t)ROWS * NH;        //    262,144
  const size_t N_ACS = (size_t)1024 * 256;       //    262,144
  const size_t N_TOT = 1024;
  const size_t N_ST  = (size_t)1024 * HD * DS;   //  8,388,608
  const size_t need  = (N_ZX + N_XC + N_DT + N_ACS + N_TOT + N_ST) * sizeof(float);
  if (ws_size < need) return;   // clean failure (diagnoses ws budget) instead of OOB fault

  float* zx     = (float*)d_ws;
  float* xconv  = zx     + N_ZX;
  float* dtv    = xconv  + N_XC;
  float* acsb   = dtv    + N_DT;
  float* totals = acsb   + N_ACS;
  float* states = totals + N_TOT;          // becomes prev_states in-place
  float* ypre   = zx + 2048;               // overlay: zx cols 2048..4095 (dead raw-xBC)

  // 1. in_proj: zx = u @ W_in^T   (8192 x 4384 x 1024)
  gemm_bt_f32<<<dim3(35, 64), 256, 0, stream>>>(u, W_in, zx, ROWS, 4384, 1024,
                                                1024, 1024, ZX_LD);
  // 2. depthwise conv + silu
  conv_silu_kernel<<<dim3(9, ROWS), 256, 0, stream>>>(zx, conv_w, conv_b, xconv);
  // 3. dt softplus
  dt_kernel<<<dim3((ROWS * NH) / 256), 256, 0, stream>>>(zx, dt_bias, dtv);
  // 4. per-chunk cumsum + states
  chunk_states_kernel<<<dim3(1024), 256, 0, stream>>>(dtv, A_log, xconv, acsb, totals, states);
  // 5. inter-chunk state scan (in place: states -> prev_states)
  chunk_prefix_kernel<<<dim3(64), 256, 0, stream>>>(states, totals);
  // 6. intra-chunk Y (diag + off) + x*D  -> ypre overlay in zx
  y_kernel<<<dim3(4096), 256, 0, stream>>>(xconv, dtv, acsb, states, Dv, ypre, ZX_LD);
  // 7. gated rmsnorm (in place on overlay)
  rmsnorm_gate_kernel<<<dim3(ROWS), 256, 0, stream>>>(zx, norm_w);
  // 8. out_proj: out = ypre @ W_out^T  (8192 x 1024 x 2048)
  gemm_bt_f32<<<dim3(8, 64), 256, 0, stream>>>(ypre, W_out, out, ROWS, 1024, 2048,
                                               ZX_LD, 2048, 1024);
}

// Round 4
// 938.826 us; speedup vs baseline: 2.1890x; 2.1890x over previous
//
#include <hip/hip_runtime.h>
#include <hip/hip_bf16.h>

// ---- problem constants ----
#define ZX_LD   4384   // in_proj output width (z 2048 | xBC 2304 | dt 32)
#define XC_LD   2304   // conv dim (x 2048 | B 128 | C 128)
#define NH      32
#define HD      64
#define DS      128
#define CHK     256
#define NC      16
#define LTOT    4096
#define ROWS    8192   // BATCH * SEQLEN
#define DSSM    2048

typedef __bf16 bf16_t;
typedef bf16_t bf16x8 __attribute__((ext_vector_type(8)));
typedef float  f32x4  __attribute__((ext_vector_type(4)));
typedef unsigned short u16x8 __attribute__((ext_vector_type(8)));
typedef unsigned short u16x4 __attribute__((ext_vector_type(4)));

__device__ inline float bf2f(unsigned short u) {
  unsigned int x = ((unsigned int)u) << 16;
  float f; __builtin_memcpy(&f, &x, 4); return f;
}

#define GLOAD_LDS16(gp, lp) \
  __builtin_amdgcn_global_load_lds((const __attribute__((address_space(1))) void*)(gp), \
                                   (__attribute__((address_space(3))) void*)(lp), 16, 0, 0)

// =====================================================================
// cast fp32 -> bf16, zero-fill past nvalid (nvalid multiple of 8)
// =====================================================================
__global__ __launch_bounds__(256) void cast_f32_bf16(
    const float* __restrict__ in, bf16_t* __restrict__ out,
    long nvalid, long total)
{
  const long e0 = ((long)blockIdx.x * 256 + threadIdx.x) * 8;
  if (e0 >= total) return;
  bf16x8 o;
  if (e0 + 8 <= nvalid) {
    const float4 a = *(const float4*)(in + e0);
    const float4 b = *(const float4*)(in + e0 + 4);
    o[0]=(bf16_t)a.x; o[1]=(bf16_t)a.y; o[2]=(bf16_t)a.z; o[3]=(bf16_t)a.w;
    o[4]=(bf16_t)b.x; o[5]=(bf16_t)b.y; o[6]=(bf16_t)b.z; o[7]=(bf16_t)b.w;
  } else {
#pragma unroll
    for (int j = 0; j < 8; ++j) o[j] = (bf16_t)0.f;
  }
  *(bf16x8*)(out + e0) = o;
}

// =====================================================================
// bf16 MFMA GEMM: C[m][n] = sum_k A[m][k]*B[n][k]
// A: M x K bf16 (lda), B: N x K bf16 (ldb, rows padded so bn+127 in range),
// C: f32 (ldc), store guarded n<N. 128x128 tile, BK=32, 256 thr (4 waves),
// each wave 64x64 via 4x4 frags of 16x16x32. m97-style 2-barrier loop.
// =====================================================================
__global__ __launch_bounds__(256) void gemm_bt_mfma(
    const bf16_t* __restrict__ A, const bf16_t* __restrict__ B,
    float* __restrict__ C, int M, int N, int K,
    int lda, int ldb, int ldc)
{
  __shared__ __align__(16) bf16_t As[128 * 32];
  __shared__ __align__(16) bf16_t Bs[128 * 32];
  const int tid  = threadIdx.x;
  const int lane = tid & 63;
  const int wave = tid >> 6;
  const int bm = blockIdx.y * 128;
  const int bn = blockIdx.x * 128;
  const int wr = (wave >> 1) * 64;   // wave row offset within tile
  const int wc = (wave & 1) * 64;    // wave col offset

  // staging assignment: wave stages chunks 2w,2w+1 of both A and B
  const int c0   = wave * 2;
  const int lrow = lane >> 2;          // 0..15 within chunk
  const int lcol = (lane & 3) * 8;     // k element offset (8 bf16 = 16B)
  const bf16_t* Ag0 = A + (size_t)(bm + c0 * 16 + lrow) * lda + lcol;
  const bf16_t* Ag1 = A + (size_t)(bm + c0 * 16 + 16 + lrow) * lda + lcol;
  const bf16_t* Bg0 = B + (size_t)(bn + c0 * 16 + lrow) * ldb + lcol;
  const bf16_t* Bg1 = B + (size_t)(bn + c0 * 16 + 16 + lrow) * ldb + lcol;
  bf16_t* Al0 = As + c0 * 512;       // wave-uniform LDS bases (1KB chunks)
  bf16_t* Al1 = As + c0 * 512 + 512;
  bf16_t* Bl0 = Bs + c0 * 512;
  bf16_t* Bl1 = Bs + c0 * 512 + 512;

  f32x4 acc[4][4];
#pragma unroll
  for (int i = 0; i < 4; ++i)
#pragma unroll
    for (int j = 0; j < 4; ++j) acc[i][j] = (f32x4){0.f, 0.f, 0.f, 0.f};

  const int nk = K >> 5;
  for (int kt = 0; kt < nk; ++kt) {
    const int k0 = kt * 32;
    __syncthreads();
    GLOAD_LDS16(Ag0 + k0, Al0);
    GLOAD_LDS16(Ag1 + k0, Al1);
    GLOAD_LDS16(Bg0 + k0, Bl0);
    GLOAD_LDS16(Bg1 + k0, Bl1);
    __syncthreads();

    const bf16_t* Ab = As + (wr + (lane & 15)) * 32 + (lane >> 4) * 8;
    const bf16_t* Bb = Bs + (wc + (lane & 15)) * 32 + (lane >> 4) * 8;
    bf16x8 af[4], bfv[4];
#pragma unroll
    for (int mi = 0; mi < 4; ++mi) af[mi]  = *(const bf16x8*)(Ab + mi * 512);
#pragma unroll
    for (int ni = 0; ni < 4; ++ni) bfv[ni] = *(const bf16x8*)(Bb + ni * 512);
#pragma unroll
    for (int mi = 0; mi < 4; ++mi)
#pragma unroll
      for (int ni = 0; ni < 4; ++ni)
        acc[mi][ni] = __builtin_amdgcn_mfma_f32_16x16x32_bf16(af[mi], bfv[ni], acc[mi][ni], 0, 0, 0);
  }

  // epilogue: C/D layout col=lane&15, row=(lane>>4)*4+j
  const int crow0 = bm + wr + (lane >> 4) * 4;
  const int ccol0 = bn + wc + (lane & 15);
#pragma unroll
  for (int ni = 0; ni < 4; ++ni) {
    const int ccol = ccol0 + ni * 16;
    if (ccol < N) {
#pragma unroll
      for (int mi = 0; mi < 4; ++mi) {
#pragma unroll
        for (int j = 0; j < 4; ++j) {
          C[(size_t)(crow0 + mi * 16 + j) * ldc + ccol] = acc[mi][ni][j];
        }
      }
    }
  }
}

// =====================================================================
// depthwise causal conv (k=4) + bias + SiLU; writes bf16 xconv
// =====================================================================
__global__ __launch_bounds__(256) void conv_silu_kernel(
    const float* __restrict__ zx, const float* __restrict__ cw,
    const float* __restrict__ cb, bf16_t* __restrict__ xconv)
{
  const int ch  = blockIdx.x * 256 + threadIdx.x;  // 0..2303
  const int row = blockIdx.y;                      // 0..8191
  const int l   = row & (LTOT - 1);
  float acc = cb[ch];
#pragma unroll
  for (int k = 0; k < 4; ++k) {
    const int ls = l - 3 + k;
    if (ls >= 0) acc = fmaf(zx[(size_t)(row - 3 + k) * ZX_LD + 2048 + ch], cw[ch*4 + k], acc);
  }
  const float r = acc / (1.f + __expf(-acc));   // silu
  xconv[(size_t)row * XC_LD + ch] = (bf16_t)r;
}

// =====================================================================
// dt = softplus(dt_raw + dt_bias)
// =====================================================================
__global__ __launch_bounds__(256) void dt_kernel(
    const float* __restrict__ zx, const float* __restrict__ dtb,
    float* __restrict__ dtv)
{
  const int idx = blockIdx.x * 256 + threadIdx.x;  // < ROWS*NH
  const int row = idx >> 5;
  const int hh  = idx & 31;
  const float x = zx[(size_t)row * ZX_LD + 4352 + hh] + dtb[hh];
  dtv[idx] = (x > 20.f) ? x : log1pf(__expf(x));
}

// =====================================================================
// per (b,c,h): cumsum(dA) within chunk; chunk totals; chunk states
// states[p][n] = sum_l B[l,n] * exp(Acs[255]-Acs[l]) * dt[l] * x[l,p]
// =====================================================================
__global__ __launch_bounds__(256) void chunk_states_kernel(
    const float* __restrict__ dtv, const float* __restrict__ A_log,
    const bf16_t* __restrict__ xconv,
    float* __restrict__ acs, float* __restrict__ totals,
    float* __restrict__ states)
{
  const int bid = blockIdx.x;          // ((b*16+c)*32+h)
  const int h = bid & 31;
  const int c = (bid >> 5) & 15;
  const int b = bid >> 9;
  const int rowbase = b * LTOT + c * CHK;
  const int l = threadIdx.x;

  __shared__ float sWdt[256];
  __shared__ float wsum[4];
  __shared__ float xw[64][68];     // [l][p] : x*dt*decay
  __shared__ float Bsh[64][132];   // [l][n]

  const float dt = dtv[(size_t)(rowbase + l) * NH + h];
  const float Ah = -__expf(A_log[h]);
  float v = dt * Ah;
#pragma unroll
  for (int off = 1; off < 64; off <<= 1) {
    float up = __shfl_up(v, off, 64);
    if ((l & 63) >= off) v += up;
  }
  if ((l & 63) == 63) wsum[l >> 6] = v;
  __syncthreads();
  const float w0 = wsum[0], w1 = wsum[1], w2 = wsum[2], w3 = wsum[3];
  const int wid = l >> 6;
  float base = 0.f;
  if (wid > 0) base += w0;
  if (wid > 1) base += w1;
  if (wid > 2) base += w2;
  const float acsl  = v + base;
  const float total = w0 + w1 + w2 + w3;
  acs[bid * 256 + l] = acsl;
  if (l == 0) totals[(b * 32 + h) * 16 + c] = total;
  sWdt[l] = __expf(total - acsl) * dt;

  const int tx = l & 15;   // n-dir
  const int ty = l >> 4;   // p-dir
  const int r  = l >> 2;   // staging row
  float acc[4][8];
#pragma unroll
  for (int i = 0; i < 4; ++i)
#pragma unroll
    for (int j = 0; j < 8; ++j) acc[i][j] = 0.f;

  for (int ls = 0; ls < 4; ++ls) {
    const int l0 = ls * 64;
    __syncthreads();
    {
      const float wgt = sWdt[l0 + r];
      const bf16_t* xrow = xconv + (size_t)(rowbase + l0 + r) * XC_LD + h * HD + (l & 3) * 16;
      float* xd = &xw[r][(l & 3) * 16];
      const u16x8* xp = (const u16x8*)xrow;
#pragma unroll
      for (int q = 0; q < 2; ++q) {
        u16x8 t = xp[q];
#pragma unroll
        for (int j = 0; j < 8; ++j) xd[q*8 + j] = bf2f(t[j]) * wgt;
      }
      const bf16_t* br = xconv + (size_t)(rowbase + l0 + r) * XC_LD + 2048 + (l & 3) * 32;
      float* bd = &Bsh[r][(l & 3) * 32];
      const u16x8* bp = (const u16x8*)br;
#pragma unroll
      for (int q = 0; q < 4; ++q) {
        u16x8 t = bp[q];
#pragma unroll
        for (int j = 0; j < 8; ++j) bd[q*8 + j] = bf2f(t[j]);
      }
    }
    __syncthreads();
#pragma unroll 8
    for (int s = 0; s < 64; ++s) {
      float4 pa = *(const float4*)&xw[s][ty*4];
      float4 b0 = *(const float4*)&Bsh[s][tx*4];
      float4 b1 = *(const float4*)&Bsh[s][64 + tx*4];
      float am[4] = {pa.x, pa.y, pa.z, pa.w};
      float bb[8] = {b0.x,b0.y,b0.z,b0.w,b1.x,b1.y,b1.z,b1.w};
#pragma unroll
      for (int i = 0; i < 4; ++i)
#pragma unroll
        for (int j = 0; j < 8; ++j) acc[i][j] = fmaf(am[i], bb[j], acc[i][j]);
    }
  }
  const size_t sbase = (size_t)bid * (HD * DS);
#pragma unroll
  for (int i = 0; i < 4; ++i) {
    const int p = ty * 4 + i;
#pragma unroll
    for (int j = 0; j < 8; ++j) {
      const int n = (j < 4) ? (tx*4 + j) : (64 + tx*4 + (j - 4));
      states[sbase + p * DS + n] = acc[i][j];
    }
  }
}

// =====================================================================
// inter-chunk scan per (b,h), IN PLACE
// =====================================================================
__global__ __launch_bounds__(256) void chunk_prefix_kernel(
    float* __restrict__ st, const float* __restrict__ totals)
{
  const int bh = blockIdx.x;   // b*32+h
  const int b = bh >> 5;
  const int h = bh & 31;
  const int tid = threadIdx.x;
  float P[32];
#pragma unroll
  for (int e = 0; e < 32; ++e) P[e] = 0.f;
  for (int c = 0; c < NC; ++c) {
    const size_t base = (size_t)((b * 16 + c) * 32 + h) * (HD * DS);
    const float g = __expf(totals[bh * 16 + c]);
#pragma unroll
    for (int e = 0; e < 32; ++e) {
      const size_t idx = base + e * 256 + tid;
      const float s = st[idx];
      st[idx] = P[e];
      P[e] = fmaf(P[e], g, s);
    }
  }
}

// =====================================================================
// Y kernel per (b,c,h,l-tile) — bf16 xconv operands, fp32 math
// =====================================================================
__global__ __launch_bounds__(256) void y_kernel(
    const bf16_t* __restrict__ xconv, const float* __restrict__ dtv,
    const float* __restrict__ acs,   const float* __restrict__ prevst,
    const float* __restrict__ Dv,    float* __restrict__ ypre, int ypld)
{
  const int bid = blockIdx.x;            // (((b*16+c)*32+h)*4+lt)
  const int lt = bid & 3;
  const int h  = (bid >> 2) & 31;
  const int c  = (bid >> 7) & 15;
  const int b  = bid >> 11;
  const int bch = (b * 16 + c) * 32 + h;
  const int rowbase = b * LTOT + c * CHK;
  const int tid = threadIdx.x;
  const int tx = tid & 15;
  const int ty = tid >> 4;
  const int r  = tid >> 2;
  const int q8 = (tid & 3) * 8;

  __shared__ float sAcs[256];
  __shared__ float sDt[256];
  __shared__ float Cst[32][68];
  __shared__ float Bst[32][68];
  __shared__ float Sst[64][68];
  __shared__ float xs[64][68];

  sAcs[tid] = acs[bch * 256 + tid];
  sDt[tid]  = dtv[(size_t)(rowbase + tid) * NH + h];

  float yacc[4][4];
#pragma unroll
  for (int i = 0; i < 4; ++i)
#pragma unroll
    for (int j = 0; j < 4; ++j) yacc[i][j] = 0.f;

  // ---- phase 1: Y_off = (C @ P^T) ----
  for (int n0 = 0; n0 < DS; n0 += 32) {
    __syncthreads();
    {
      const bf16_t* crow = xconv + (size_t)(rowbase + lt*64 + r) * XC_LD + 2176 + n0 + q8;
      u16x8 cu = *(const u16x8*)crow;
#pragma unroll
      for (int j = 0; j < 8; ++j) Cst[q8 + j][r] = bf2f(cu[j]);
      const float* prow = prevst + (size_t)bch * (HD * DS) + r * DS + n0 + q8;
      float4 p0 = *(const float4*)(prow);
      float4 p1 = *(const float4*)(prow + 4);
      Bst[q8+0][r]=p0.x; Bst[q8+1][r]=p0.y; Bst[q8+2][r]=p0.z; Bst[q8+3][r]=p0.w;
      Bst[q8+4][r]=p1.x; Bst[q8+5][r]=p1.y; Bst[q8+6][r]=p1.z; Bst[q8+7][r]=p1.w;
    }
    __syncthreads();
#pragma unroll 8
    for (int nn = 0; nn < 32; ++nn) {
      float4 ca = *(const float4*)&Cst[nn][ty*4];
      float4 pb = *(const float4*)&Bst[nn][tx*4];
      float am[4] = {ca.x, ca.y, ca.z, ca.w};
      float bb[4] = {pb.x, pb.y, pb.z, pb.w};
#pragma unroll
      for (int i = 0; i < 4; ++i)
#pragma unroll
        for (int j = 0; j < 4; ++j) yacc[i][j] = fmaf(am[i], bb[j], yacc[i][j]);
    }
  }
#pragma unroll
  for (int i = 0; i < 4; ++i) {
    const float e = __expf(sAcs[lt*64 + ty*4 + i]);
#pragma unroll
    for (int j = 0; j < 4; ++j) yacc[i][j] *= e;
  }

  // ---- phase 2: causal diagonal tiles ----
  for (int st = 0; st <= lt; ++st) {
    float sacc[4][4];
#pragma unroll
    for (int i = 0; i < 4; ++i)
#pragma unroll
      for (int j = 0; j < 4; ++j) sacc[i][j] = 0.f;

    for (int n0 = 0; n0 < DS; n0 += 32) {
      __syncthreads();
      {
        const bf16_t* crow = xconv + (size_t)(rowbase + lt*64 + r) * XC_LD + 2176 + n0 + q8;
        u16x8 cu = *(const u16x8*)crow;
#pragma unroll
        for (int j = 0; j < 8; ++j) Cst[q8 + j][r] = bf2f(cu[j]);
        const bf16_t* brow = xconv + (size_t)(rowbase + st*64 + r) * XC_LD + 2048 + n0 + q8;
        u16x8 bu = *(const u16x8*)brow;
#pragma unroll
        for (int j = 0; j < 8; ++j) Bst[q8 + j][r] = bf2f(bu[j]);
      }
      __syncthreads();
#pragma unroll 8
      for (int nn = 0; nn < 32; ++nn) {
        float4 ca = *(const float4*)&Cst[nn][ty*4];
        float4 bb4 = *(const float4*)&Bst[nn][tx*4];
        float am[4] = {ca.x, ca.y, ca.z, ca.w};
        float bb[4] = {bb4.x, bb4.y, bb4.z, bb4.w};
#pragma unroll
        for (int i = 0; i < 4; ++i)
#pragma unroll
          for (int j = 0; j < 4; ++j) sacc[i][j] = fmaf(am[i], bb[j], sacc[i][j]);
      }
    }
    __syncthreads();
#pragma unroll
    for (int j = 0; j < 4; ++j) {
      const int sj = st*64 + tx*4 + j;
      const float dts = sDt[sj];
      const float as  = sAcs[sj];
#pragma unroll
      for (int i = 0; i < 4; ++i) {
        const int li = lt*64 + ty*4 + i;
        float wv = 0.f;
        if (li >= sj) wv = sacc[i][j] * __expf(sAcs[li] - as) * dts;
        Sst[tx*4 + j][ty*4 + i] = wv;
      }
    }
    {
      const int q16 = (tid & 3) * 16;
      const bf16_t* xrow = xconv + (size_t)(rowbase + st*64 + r) * XC_LD + h * HD + q16;
      const u16x8* xp = (const u16x8*)xrow;
#pragma unroll
      for (int q = 0; q < 2; ++q) {
        u16x8 t = xp[q];
#pragma unroll
        for (int j = 0; j < 8; ++j) xs[r][q16 + q*8 + j] = bf2f(t[j]);
      }
    }
    __syncthreads();
#pragma unroll 8
    for (int s = 0; s < 64; ++s) {
      float4 wv4 = *(const float4*)&Sst[s][ty*4];
      float4 xv4 = *(const float4*)&xs[s][tx*4];
      float am[4] = {wv4.x, wv4.y, wv4.z, wv4.w};
      float bb[4] = {xv4.x, xv4.y, xv4.z, xv4.w};
#pragma unroll
      for (int i = 0; i < 4; ++i)
#pragma unroll
        for (int j = 0; j < 4; ++j) yacc[i][j] = fmaf(am[i], bb[j], yacc[i][j]);
    }
  }

  // ---- epilogue: + x*D, write ypre (f32 overlay, strided) ----
  const float Dh = Dv[h];
#pragma unroll
  for (int i = 0; i < 4; ++i) {
    const int row = rowbase + lt*64 + ty*4 + i;
    u16x4 xu = *(const u16x4*)(xconv + (size_t)row * XC_LD + h * HD + tx*4);
    float* yr = ypre + (size_t)row * ypld + h * HD + tx*4;
    yr[0] = yacc[i][0] + bf2f(xu[0]) * Dh;
    yr[1] = yacc[i][1] + bf2f(xu[1]) * Dh;
    yr[2] = yacc[i][2] + bf2f(xu[2]) * Dh;
    yr[3] = yacc[i][3] + bf2f(xu[3]) * Dh;
  }
}

// =====================================================================
// gated RMSNorm: read ypre f32 overlay (zx cols 2048..4095) + z (cols 0..2047),
// write normalized result as bf16 into ypre_bf (dense [ROWS][2048])
// =====================================================================
__global__ __launch_bounds__(256) void rmsnorm_gate_kernel(
    const float* __restrict__ zx, const float* __restrict__ normw,
    bf16_t* __restrict__ ypre_bf)
{
  const int row = blockIdx.x;
  const int tid = threadIdx.x;
  float vals[8];
  float ss = 0.f;
#pragma unroll
  for (int e = 0; e < 8; ++e) {
    const int col = e * 256 + tid;
    const float y = zx[(size_t)row * ZX_LD + 2048 + col];
    const float z = zx[(size_t)row * ZX_LD + col];
    const float sz = z / (1.f + __expf(-z));
    const float v = y * sz;
    vals[e] = v;
    ss += v * v;
  }
#pragma unroll
  for (int off = 32; off >= 1; off >>= 1) ss += __shfl_xor(ss, off, 64);
  __shared__ float red[4];
  if ((tid & 63) == 0) red[tid >> 6] = ss;
  __syncthreads();
  const float tot = red[0] + red[1] + red[2] + red[3];
  const float scale = rsqrtf(tot / (float)DSSM + 1e-5f);
#pragma unroll
  for (int e = 0; e < 8; ++e) {
    const int col = e * 256 + tid;
    ypre_bf[(size_t)row * DSSM + col] = (bf16_t)(vals[e] * scale * normw[col]);
  }
}

// =====================================================================
extern "C" void kernel_launch(void* const* d_in, const int* in_sizes, int n_in,
                              void* d_out, int out_size, void* d_ws, size_t ws_size,
                              hipStream_t stream)
{
  const float* u       = (const float*)d_in[0];
  const float* W_in    = (const float*)d_in[1];
  const float* conv_w  = (const float*)d_in[2];
  const float* conv_b  = (const float*)d_in[3];
  const float* dt_bias = (const float*)d_in[4];
  const float* A_log   = (const float*)d_in[5];
  const float* Dv      = (const float*)d_in[6];
  const float* norm_w  = (const float*)d_in[7];
  const float* W_out   = (const float*)d_in[8];
  float* out = (float*)d_out;

  // ---- workspace layout (byte offsets), total 254,808,064 B = 243.0 MiB ----
  const size_t OFF_XC  = (size_t)ROWS * ZX_LD * 4;            // 143,654,912
  const size_t OFF_DT  = OFF_XC  + (size_t)ROWS * XC_LD * 2;  // +37,748,736
  const size_t OFF_ACS = OFF_DT  + (size_t)ROWS * NH * 4;     // +1,048,576
  const size_t OFF_TOT = OFF_ACS + (size_t)1024 * 256 * 4;    // +1,048,576
  const size_t OFF_ST  = OFF_TOT + 4096;
  const size_t OFF_AR  = OFF_ST  + (size_t)1024 * HD * DS * 4; // +33,554,432
  const size_t need    = OFF_AR  + (size_t)ROWS * XC_LD * 2;   // arena 37,748,736
  if (ws_size < need) return;

  char* w = (char*)d_ws;
  float*  zx      = (float*)w;
  bf16_t* xconv   = (bf16_t*)(w + OFF_XC);
  float*  dtv     = (float*)(w + OFF_DT);
  float*  acsb    = (float*)(w + OFF_ACS);
  float*  totals  = (float*)(w + OFF_TOT);
  float*  states  = (float*)(w + OFF_ST);       // becomes prev_states in-place
  bf16_t* arena   = (bf16_t*)(w + OFF_AR);
  // arena phase 1 (in_proj): u_bf [0 .. 8M), Wpad [8M .. 12.97M) elems
  bf16_t* u_bf    = arena;
  bf16_t* Wpad    = arena + (size_t)ROWS * 1024;          // [4480][1024]
  // arena phase 2 (out_proj): ypre_bf [0 .. 16.77M), Wout_bf [16.77M .. 18.87M)
  bf16_t* ypre_bf = arena;
  bf16_t* Wout_bf = arena + (size_t)ROWS * DSSM;
  float*  ypre    = zx + 2048;   // f32 overlay: zx cols 2048..4095 (dead raw-xBC)

  // 0. casts for in_proj (+ W_out cast; its arena range doesn't overlap phase 1)
  {
    const long n_u = (long)ROWS * 1024;
    cast_f32_bf16<<<dim3((n_u/8 + 255)/256), 256, 0, stream>>>(u, u_bf, n_u, n_u);
    const long n_wv = (long)4384 * 1024, n_wt = (long)4480 * 1024;
    cast_f32_bf16<<<dim3((n_wt/8 + 255)/256), 256, 0, stream>>>(W_in, Wpad, n_wv, n_wt);
    const long n_wo = (long)1024 * DSSM;
    cast_f32_bf16<<<dim3((n_wo/8 + 255)/256), 256, 0, stream>>>(W_out, Wout_bf, n_wo, n_wo);
  }
  // 1. in_proj: zx = u @ W_in^T   (8192 x 4384 x 1024), MFMA bf16
  gemm_bt_mfma<<<dim3(35, 64), 256, 0, stream>>>(u_bf, Wpad, zx, ROWS, 4384, 1024,
                                                 1024, 1024, ZX_LD);
  // 2. depthwise conv + silu -> bf16 xconv
  conv_silu_kernel<<<dim3(9, ROWS), 256, 0, stream>>>(zx, conv_w, conv_b, xconv);
  // 3. dt softplus
  dt_kernel<<<dim3((ROWS * NH) / 256), 256, 0, stream>>>(zx, dt_bias, dtv);
  // 4. per-chunk cumsum + states
  chunk_states_kernel<<<dim3(1024), 256, 0, stream>>>(dtv, A_log, xconv, acsb, totals, states);
  // 5. inter-chunk state scan (in place: states -> prev_states)
  chunk_prefix_kernel<<<dim3(64), 256, 0, stream>>>(states, totals);
  // 6. intra-chunk Y (diag + off) + x*D  -> ypre f32 overlay in zx
  y_kernel<<<dim3(4096), 256, 0, stream>>>(xconv, dtv, acsb, states, Dv, ypre, ZX_LD);
  // 7. gated rmsnorm -> ypre_bf (bf16, overwrites u_bf/Wpad region: both dead)
  rmsnorm_gate_kernel<<<dim3(ROWS), 256, 0, stream>>>(zx, norm_w, ypre_bf);
  // 8. out_proj: out = ypre @ W_out^T  (8192 x 1024 x 2048), MFMA bf16
  gemm_bt_mfma<<<dim3(8, 64), 256, 0, stream>>>(ypre_bf, Wout_bf, out, ROWS, 1024, 2048,
                                                2048, 2048, 1024);
}

// Round 5
// 587.427 us; speedup vs baseline: 3.4985x; 1.5982x over previous
//
#include <hip/hip_runtime.h>
#include <hip/hip_bf16.h>

// ---- problem constants ----
#define ZX_LD   4384   // in_proj output width (z 2048 | xBC 2304 | dt 32)
#define XC_LD   2304   // conv dim (x 2048 | B 128 | C 128)
#define NH      32
#define HD      64
#define DS      128
#define CHK     256
#define NC      16
#define LTOT    4096
#define ROWS    8192   // BATCH * SEQLEN
#define DSSM    2048
#define YPAD    80     // Sl/xT row stride (bf16): 160B, 16B-aligned for b128

typedef __bf16 bf16_t;
typedef bf16_t bf16x8 __attribute__((ext_vector_type(8)));
typedef float  f32x4  __attribute__((ext_vector_type(4)));
typedef unsigned short u16x8 __attribute__((ext_vector_type(8)));
typedef unsigned short u16x4 __attribute__((ext_vector_type(4)));

__device__ inline float bf2f(unsigned short u) {
  unsigned int x = ((unsigned int)u) << 16;
  float f; __builtin_memcpy(&f, &x, 4); return f;
}

#define GLOAD_LDS16(gp, lp) \
  __builtin_amdgcn_global_load_lds((const __attribute__((address_space(1))) void*)(gp), \
                                   (__attribute__((address_space(3))) void*)(lp), 16, 0, 0)

// =====================================================================
// cast fp32 -> bf16, zero-fill past nvalid (nvalid multiple of 8)
// =====================================================================
__global__ __launch_bounds__(256) void cast_f32_bf16(
    const float* __restrict__ in, bf16_t* __restrict__ out,
    long nvalid, long total)
{
  const long e0 = ((long)blockIdx.x * 256 + threadIdx.x) * 8;
  if (e0 >= total) return;
  bf16x8 o;
  if (e0 + 8 <= nvalid) {
    const float4 a = *(const float4*)(in + e0);
    const float4 b = *(const float4*)(in + e0 + 4);
    o[0]=(bf16_t)a.x; o[1]=(bf16_t)a.y; o[2]=(bf16_t)a.z; o[3]=(bf16_t)a.w;
    o[4]=(bf16_t)b.x; o[5]=(bf16_t)b.y; o[6]=(bf16_t)b.z; o[7]=(bf16_t)b.w;
  } else {
#pragma unroll
    for (int j = 0; j < 8; ++j) o[j] = (bf16_t)0.f;
  }
  *(bf16x8*)(out + e0) = o;
}

// =====================================================================
// bf16 MFMA GEMM: C[m][n] = sum_k A[m][k]*B[n][k]  (m97-style 2-barrier)
// =====================================================================
__global__ __launch_bounds__(256) void gemm_bt_mfma(
    const bf16_t* __restrict__ A, const bf16_t* __restrict__ B,
    float* __restrict__ C, int M, int N, int K,
    int lda, int ldb, int ldc)
{
  __shared__ __align__(16) bf16_t As[128 * 32];
  __shared__ __align__(16) bf16_t Bs[128 * 32];
  const int tid  = threadIdx.x;
  const int lane = tid & 63;
  const int wave = tid >> 6;
  const int bm = blockIdx.y * 128;
  const int bn = blockIdx.x * 128;
  const int wr = (wave >> 1) * 64;
  const int wc = (wave & 1) * 64;

  const int c0   = wave * 2;
  const int lrow = lane >> 2;
  const int lcol = (lane & 3) * 8;
  const bf16_t* Ag0 = A + (size_t)(bm + c0 * 16 + lrow) * lda + lcol;
  const bf16_t* Ag1 = A + (size_t)(bm + c0 * 16 + 16 + lrow) * lda + lcol;
  const bf16_t* Bg0 = B + (size_t)(bn + c0 * 16 + lrow) * ldb + lcol;
  const bf16_t* Bg1 = B + (size_t)(bn + c0 * 16 + 16 + lrow) * ldb + lcol;
  bf16_t* Al0 = As + c0 * 512;
  bf16_t* Al1 = As + c0 * 512 + 512;
  bf16_t* Bl0 = Bs + c0 * 512;
  bf16_t* Bl1 = Bs + c0 * 512 + 512;

  f32x4 acc[4][4];
#pragma unroll
  for (int i = 0; i < 4; ++i)
#pragma unroll
    for (int j = 0; j < 4; ++j) acc[i][j] = (f32x4){0.f, 0.f, 0.f, 0.f};

  const int nk = K >> 5;
  for (int kt = 0; kt < nk; ++kt) {
    const int k0 = kt * 32;
    __syncthreads();
    GLOAD_LDS16(Ag0 + k0, Al0);
    GLOAD_LDS16(Ag1 + k0, Al1);
    GLOAD_LDS16(Bg0 + k0, Bl0);
    GLOAD_LDS16(Bg1 + k0, Bl1);
    __syncthreads();

    const bf16_t* Ab = As + (wr + (lane & 15)) * 32 + (lane >> 4) * 8;
    const bf16_t* Bb = Bs + (wc + (lane & 15)) * 32 + (lane >> 4) * 8;
    bf16x8 af[4], bfv[4];
#pragma unroll
    for (int mi = 0; mi < 4; ++mi) af[mi]  = *(const bf16x8*)(Ab + mi * 512);
#pragma unroll
    for (int ni = 0; ni < 4; ++ni) bfv[ni] = *(const bf16x8*)(Bb + ni * 512);
#pragma unroll
    for (int mi = 0; mi < 4; ++mi)
#pragma unroll
      for (int ni = 0; ni < 4; ++ni)
        acc[mi][ni] = __builtin_amdgcn_mfma_f32_16x16x32_bf16(af[mi], bfv[ni], acc[mi][ni], 0, 0, 0);
  }

  const int crow0 = bm + wr + (lane >> 4) * 4;
  const int ccol0 = bn + wc + (lane & 15);
#pragma unroll
  for (int ni = 0; ni < 4; ++ni) {
    const int ccol = ccol0 + ni * 16;
    if (ccol < N) {
#pragma unroll
      for (int mi = 0; mi < 4; ++mi) {
#pragma unroll
        for (int j = 0; j < 4; ++j) {
          C[(size_t)(crow0 + mi * 16 + j) * ldc + ccol] = acc[mi][ni][j];
        }
      }
    }
  }
}

// =====================================================================
// depthwise causal conv (k=4) + bias + SiLU; writes bf16 xconv
// =====================================================================
__global__ __launch_bounds__(256) void conv_silu_kernel(
    const float* __restrict__ zx, const float* __restrict__ cw,
    const float* __restrict__ cb, bf16_t* __restrict__ xconv)
{
  const int ch  = blockIdx.x * 256 + threadIdx.x;  // 0..2303
  const int row = blockIdx.y;                      // 0..8191
  const int l   = row & (LTOT - 1);
  float acc = cb[ch];
#pragma unroll
  for (int k = 0; k < 4; ++k) {
    const int ls = l - 3 + k;
    if (ls >= 0) acc = fmaf(zx[(size_t)(row - 3 + k) * ZX_LD + 2048 + ch], cw[ch*4 + k], acc);
  }
  const float r = acc / (1.f + __expf(-acc));   // silu
  xconv[(size_t)row * XC_LD + ch] = (bf16_t)r;
}

// =====================================================================
// dt = softplus(dt_raw + dt_bias)
// =====================================================================
__global__ __launch_bounds__(256) void dt_kernel(
    const float* __restrict__ zx, const float* __restrict__ dtb,
    float* __restrict__ dtv)
{
  const int idx = blockIdx.x * 256 + threadIdx.x;  // < ROWS*NH
  const int row = idx >> 5;
  const int hh  = idx & 31;
  const float x = zx[(size_t)row * ZX_LD + 4352 + hh] + dtb[hh];
  dtv[idx] = (x > 20.f) ? x : log1pf(__expf(x));
}

// =====================================================================
// per (b,c,h): cumsum(dA) within chunk; chunk totals; chunk states
// =====================================================================
__global__ __launch_bounds__(256) void chunk_states_kernel(
    const float* __restrict__ dtv, const float* __restrict__ A_log,
    const bf16_t* __restrict__ xconv,
    float* __restrict__ acs, float* __restrict__ totals,
    float* __restrict__ states)
{
  const int bid = blockIdx.x;          // ((b*16+c)*32+h)
  const int h = bid & 31;
  const int c = (bid >> 5) & 15;
  const int b = bid >> 9;
  const int rowbase = b * LTOT + c * CHK;
  const int l = threadIdx.x;

  __shared__ float sWdt[256];
  __shared__ float wsum[4];
  __shared__ float xw[64][68];     // [l][p]
  __shared__ float Bsh[64][132];   // [l][n]

  const float dt = dtv[(size_t)(rowbase + l) * NH + h];
  const float Ah = -__expf(A_log[h]);
  float v = dt * Ah;
#pragma unroll
  for (int off = 1; off < 64; off <<= 1) {
    float up = __shfl_up(v, off, 64);
    if ((l & 63) >= off) v += up;
  }
  if ((l & 63) == 63) wsum[l >> 6] = v;
  __syncthreads();
  const float w0 = wsum[0], w1 = wsum[1], w2 = wsum[2], w3 = wsum[3];
  const int wid = l >> 6;
  float base = 0.f;
  if (wid > 0) base += w0;
  if (wid > 1) base += w1;
  if (wid > 2) base += w2;
  const float acsl  = v + base;
  const float total = w0 + w1 + w2 + w3;
  acs[bid * 256 + l] = acsl;
  if (l == 0) totals[(b * 32 + h) * 16 + c] = total;
  sWdt[l] = __expf(total - acsl) * dt;

  const int tx = l & 15;
  const int ty = l >> 4;
  const int r  = l >> 2;
  float acc[4][8];
#pragma unroll
  for (int i = 0; i < 4; ++i)
#pragma unroll
    for (int j = 0; j < 8; ++j) acc[i][j] = 0.f;

  for (int ls = 0; ls < 4; ++ls) {
    const int l0 = ls * 64;
    __syncthreads();
    {
      const float wgt = sWdt[l0 + r];
      const bf16_t* xrow = xconv + (size_t)(rowbase + l0 + r) * XC_LD + h * HD + (l & 3) * 16;
      float* xd = &xw[r][(l & 3) * 16];
      const u16x8* xp = (const u16x8*)xrow;
#pragma unroll
      for (int q = 0; q < 2; ++q) {
        u16x8 t = xp[q];
#pragma unroll
        for (int j = 0; j < 8; ++j) xd[q*8 + j] = bf2f(t[j]) * wgt;
      }
      const bf16_t* br = xconv + (size_t)(rowbase + l0 + r) * XC_LD + 2048 + (l & 3) * 32;
      float* bd = &Bsh[r][(l & 3) * 32];
      const u16x8* bp = (const u16x8*)br;
#pragma unroll
      for (int q = 0; q < 4; ++q) {
        u16x8 t = bp[q];
#pragma unroll
        for (int j = 0; j < 8; ++j) bd[q*8 + j] = bf2f(t[j]);
      }
    }
    __syncthreads();
#pragma unroll 8
    for (int s = 0; s < 64; ++s) {
      float4 pa = *(const float4*)&xw[s][ty*4];
      float4 b0 = *(const float4*)&Bsh[s][tx*4];
      float4 b1 = *(const float4*)&Bsh[s][64 + tx*4];
      float am[4] = {pa.x, pa.y, pa.z, pa.w};
      float bb[8] = {b0.x,b0.y,b0.z,b0.w,b1.x,b1.y,b1.z,b1.w};
#pragma unroll
      for (int i = 0; i < 4; ++i)
#pragma unroll
        for (int j = 0; j < 8; ++j) acc[i][j] = fmaf(am[i], bb[j], acc[i][j]);
    }
  }
  const size_t sbase = (size_t)bid * (HD * DS);
#pragma unroll
  for (int i = 0; i < 4; ++i) {
    const int p = ty * 4 + i;
#pragma unroll
    for (int j = 0; j < 8; ++j) {
      const int n = (j < 4) ? (tx*4 + j) : (64 + tx*4 + (j - 4));
      states[sbase + p * DS + n] = acc[i][j];
    }
  }
}

// =====================================================================
// inter-chunk scan per (b,h): prev-state written as BF16 to prevbf;
// states buffer left untouched.
// =====================================================================
__global__ __launch_bounds__(256) void chunk_prefix_kernel(
    const float* __restrict__ st, const float* __restrict__ totals,
    bf16_t* __restrict__ prevbf)
{
  const int bh = blockIdx.x;   // b*32+h
  const int b = bh >> 5;
  const int h = bh & 31;
  const int tid = threadIdx.x;
  float P[32];
#pragma unroll
  for (int e = 0; e < 32; ++e) P[e] = 0.f;
  for (int c = 0; c < NC; ++c) {
    const size_t base = (size_t)((b * 16 + c) * 32 + h) * (HD * DS);
    const float g = __expf(totals[bh * 16 + c]);
#pragma unroll
    for (int e = 0; e < 32; ++e) {
      const size_t idx = base + e * 256 + tid;
      prevbf[idx] = (bf16_t)P[e];
      P[e] = fmaf(P[e], g, st[idx]);
    }
  }
}

// =====================================================================
// Y kernel, MFMA version. Block = (b,c,h,lt); 4 waves, wave w owns
// output cols p in [16w,16w+16). Y[l,p] = exp(Acs[l])*(C·P^T)[l,p]
//   + sum_{st<=lt} S~ @ x  with S~ = mask(l>=s)*CB^T*exp(Acs[l]-Acs[s])*dt[s]
//   + x[l,p]*D[h]
// C staged swizzled in LDS once (persistent reg frags); B restaged per st
// (swizzled global_load_lds); x reg-staged TRANSPOSED (PV B-operand needs
// x^T[p][s]); S~ through LDS (bf16) for the layout change QK-C/D -> PV-A.
// =====================================================================
__global__ __launch_bounds__(256) void y_kernel_mfma(
    const bf16_t* __restrict__ xconv, const float* __restrict__ dtv,
    const float* __restrict__ acs,   const bf16_t* __restrict__ prevbf,
    const float* __restrict__ Dv,    float* __restrict__ ypre, int ypld)
{
  const int bid = blockIdx.x;            // (((b*16+c)*32+h)*4+lt)
  const int lt = bid & 3;
  const int h  = (bid >> 2) & 31;
  const int c  = (bid >> 7) & 15;
  const int b  = bid >> 11;
  const int bch = (b * 16 + c) * 32 + h;
  const int rowbase = b * LTOT + c * CHK;
  const int tid  = threadIdx.x;
  const int lane = tid & 63;
  const int wv   = tid >> 6;             // wave id 0..3
  const int ln15 = lane & 15;
  const int lg   = lane >> 4;            // 0..3

  __shared__ float sAcs[256];
  __shared__ float sDt[256];
  __shared__ __align__(16) bf16_t Cl[64 * 128];   // XOR-swizzled rows l
  __shared__ __align__(16) bf16_t Bl[64 * 128];   // XOR-swizzled rows s
  __shared__ __align__(16) bf16_t Sl[64 * YPAD];  // [l][s] bf16
  __shared__ __align__(16) bf16_t xT[64 * YPAD];  // [p][s] bf16
  unsigned short* xTu = (unsigned short*)xT;

  sAcs[tid] = acs[bch * 256 + tid];
  sDt[tid]  = dtv[(size_t)(rowbase + tid) * NH + h];

  // ---- stage C rows [lt*64, +64), 128 cols (xconv cols 2176..2303) ----
  // swizzle: 16B-chunk c_dst holds global chunk c_dst ^ (row&7)  (involution)
#pragma unroll
  for (int i = 0; i < 4; ++i) {
    const int chunk = wv * 4 + i;          // 1KB chunk = 4 rows
    const int r  = chunk * 4 + lg;
    const int cs = ln15 ^ (r & 7);
    const bf16_t* src = xconv + (size_t)(rowbase + lt*64 + r) * XC_LD + 2176 + cs * 8;
    GLOAD_LDS16(src, Cl + chunk * 512);
  }
  __syncthreads();

  // ---- persistent C A-frags: cf[mi][ks] ----
  bf16x8 cf[4][4];
#pragma unroll
  for (int mi = 0; mi < 4; ++mi) {
    const int row = mi * 16 + ln15;
#pragma unroll
    for (int ks = 0; ks < 4; ++ks) {
      const int chunk = (ks * 4 + lg) ^ (row & 7);
      cf[mi][ks] = *(const bf16x8*)(Cl + row * 128 + chunk * 8);
    }
  }

  // ---- CP term: acc[mi] = C·P^T for this wave's p-slice ----
  f32x4 acc[4];
#pragma unroll
  for (int mi = 0; mi < 4; ++mi) acc[mi] = (f32x4){0.f, 0.f, 0.f, 0.f};
  {
    const bf16_t* pb = prevbf + ((size_t)bch * 64 + 16 * wv + ln15) * 128 + lg * 8;
#pragma unroll
    for (int ks = 0; ks < 4; ++ks) {
      bf16x8 pf = *(const bf16x8*)(pb + ks * 32);
#pragma unroll
      for (int mi = 0; mi < 4; ++mi)
        acc[mi] = __builtin_amdgcn_mfma_f32_16x16x32_bf16(cf[mi][ks], pf, acc[mi], 0, 0, 0);
    }
  }
  // scale by exp(Acs[l])
#pragma unroll
  for (int mi = 0; mi < 4; ++mi) {
#pragma unroll
    for (int j = 0; j < 4; ++j)
      acc[mi][j] *= __expf(sAcs[lt*64 + mi*16 + lg*4 + j]);
  }

  // ---- causal st loop ----
  for (int st = 0; st <= lt; ++st) {
    __syncthreads();   // prior QK/PV done with Bl/Sl/xT
    // stage B rows [st*64,+64) (xconv cols 2048..2175), swizzled
#pragma unroll
    for (int i = 0; i < 4; ++i) {
      const int chunk = wv * 4 + i;
      const int r  = chunk * 4 + lg;
      const int cs = ln15 ^ (r & 7);
      const bf16_t* src = xconv + (size_t)(rowbase + st*64 + r) * XC_LD + 2048 + cs * 8;
      GLOAD_LDS16(src, Bl + chunk * 512);
    }
    // stage x transposed: thread handles row s=tid>>2, cols p0=(tid&3)*16
    {
      const int s  = tid >> 2;
      const int p0 = (tid & 3) * 16;
      const bf16_t* xr = xconv + (size_t)(rowbase + st*64 + s) * XC_LD + h * HD + p0;
      u16x8 v0 = *(const u16x8*)xr;
      u16x8 v1 = *(const u16x8*)(xr + 8);
#pragma unroll
      for (int j = 0; j < 8; ++j) xTu[(p0 + j) * YPAD + s] = v0[j];
#pragma unroll
      for (int j = 0; j < 8; ++j) xTu[(p0 + 8 + j) * YPAD + s] = v1[j];
    }
    __syncthreads();   // staging visible (vmcnt drained by barrier)

    // QK: S-slice cols [16wv,16wv+16)
    f32x4 sa[4];
#pragma unroll
    for (int mi = 0; mi < 4; ++mi) sa[mi] = (f32x4){0.f, 0.f, 0.f, 0.f};
    {
      const int row = 16 * wv + ln15;     // s row in Bl
#pragma unroll
      for (int ks = 0; ks < 4; ++ks) {
        const int chunk = (ks * 4 + lg) ^ (row & 7);
        bf16x8 bfr = *(const bf16x8*)(Bl + row * 128 + chunk * 8);
#pragma unroll
        for (int mi = 0; mi < 4; ++mi)
          sa[mi] = __builtin_amdgcn_mfma_f32_16x16x32_bf16(cf[mi][ks], bfr, sa[mi], 0, 0, 0);
      }
    }
    // decay * mask * dt -> bf16 -> Sl[l][s]
    {
      const int sg = st * 64 + 16 * wv + ln15;   // s within chunk
      const float as  = sAcs[sg];
      const float dts = sDt[sg];
#pragma unroll
      for (int mi = 0; mi < 4; ++mi) {
#pragma unroll
        for (int j = 0; j < 4; ++j) {
          const int lloc = mi * 16 + lg * 4 + j;
          const int ll = lt * 64 + lloc;
          float wvv = 0.f;
          if (ll >= sg) wvv = sa[mi][j] * __expf(sAcs[ll] - as) * dts;
          Sl[lloc * YPAD + 16 * wv + ln15] = (bf16_t)wvv;
        }
      }
    }
    __syncthreads();   // S visible to all waves

    // PV: acc[mi] += S~ @ x   (contraction over s, 2 k-steps of 32)
#pragma unroll
    for (int ks2 = 0; ks2 < 2; ++ks2) {
      bf16x8 xf = *(const bf16x8*)(xT + (16 * wv + ln15) * YPAD + ks2 * 32 + lg * 8);
#pragma unroll
      for (int mi = 0; mi < 4; ++mi) {
        bf16x8 sf = *(const bf16x8*)(Sl + (mi * 16 + ln15) * YPAD + ks2 * 32 + lg * 8);
        acc[mi] = __builtin_amdgcn_mfma_f32_16x16x32_bf16(sf, xf, acc[mi], 0, 0, 0);
      }
    }
  }

  // ---- epilogue: + x*D (xT holds st=lt rows = this tile's l rows) ----
  const float Dh = Dv[h];
  const int p = 16 * wv + ln15;
#pragma unroll
  for (int mi = 0; mi < 4; ++mi) {
#pragma unroll
    for (int j = 0; j < 4; ++j) {
      const int lloc = mi * 16 + lg * 4 + j;
      const int row  = rowbase + lt * 64 + lloc;
      const float xv = (float)xT[p * YPAD + lloc];
      ypre[(size_t)row * ypld + h * HD + p] = acc[mi][j] + xv * Dh;
    }
  }
}

// =====================================================================
// gated RMSNorm: read ypre f32 overlay + z, write bf16 ypre_bf
// =====================================================================
__global__ __launch_bounds__(256) void rmsnorm_gate_kernel(
    const float* __restrict__ zx, const float* __restrict__ normw,
    bf16_t* __restrict__ ypre_bf)
{
  const int row = blockIdx.x;
  const int tid = threadIdx.x;
  float vals[8];
  float ss = 0.f;
#pragma unroll
  for (int e = 0; e < 8; ++e) {
    const int col = e * 256 + tid;
    const float y = zx[(size_t)row * ZX_LD + 2048 + col];
    const float z = zx[(size_t)row * ZX_LD + col];
    const float sz = z / (1.f + __expf(-z));
    const float v = y * sz;
    vals[e] = v;
    ss += v * v;
  }
#pragma unroll
  for (int off = 32; off >= 1; off >>= 1) ss += __shfl_xor(ss, off, 64);
  __shared__ float red[4];
  if ((tid & 63) == 0) red[tid >> 6] = ss;
  __syncthreads();
  const float tot = red[0] + red[1] + red[2] + red[3];
  const float scale = rsqrtf(tot / (float)DSSM + 1e-5f);
#pragma unroll
  for (int e = 0; e < 8; ++e) {
    const int col = e * 256 + tid;
    ypre_bf[(size_t)row * DSSM + col] = (bf16_t)(vals[e] * scale * normw[col]);
  }
}

// =====================================================================
extern "C" void kernel_launch(void* const* d_in, const int* in_sizes, int n_in,
                              void* d_out, int out_size, void* d_ws, size_t ws_size,
                              hipStream_t stream)
{
  const float* u       = (const float*)d_in[0];
  const float* W_in    = (const float*)d_in[1];
  const float* conv_w  = (const float*)d_in[2];
  const float* conv_b  = (const float*)d_in[3];
  const float* dt_bias = (const float*)d_in[4];
  const float* A_log   = (const float*)d_in[5];
  const float* Dv      = (const float*)d_in[6];
  const float* norm_w  = (const float*)d_in[7];
  const float* W_out   = (const float*)d_in[8];
  float* out = (float*)d_out;

  // ---- workspace layout (byte offsets), total 254,808,064 B = 243.0 MiB ----
  const size_t OFF_XC  = (size_t)ROWS * ZX_LD * 4;
  const size_t OFF_DT  = OFF_XC  + (size_t)ROWS * XC_LD * 2;
  const size_t OFF_ACS = OFF_DT  + (size_t)ROWS * NH * 4;
  const size_t OFF_TOT = OFF_ACS + (size_t)1024 * 256 * 4;
  const size_t OFF_ST  = OFF_TOT + 4096;
  const size_t OFF_AR  = OFF_ST  + (size_t)1024 * HD * DS * 4;
  const size_t need    = OFF_AR  + (size_t)ROWS * XC_LD * 2;
  if (ws_size < need) return;

  char* w = (char*)d_ws;
  float*  zx      = (float*)w;
  bf16_t* xconv   = (bf16_t*)(w + OFF_XC);
  float*  dtv     = (float*)(w + OFF_DT);
  float*  acsb    = (float*)(w + OFF_ACS);
  float*  totals  = (float*)(w + OFF_TOT);
  float*  states  = (float*)(w + OFF_ST);
  bf16_t* arena   = (bf16_t*)(w + OFF_AR);
  // arena phase 1 (in_proj): u_bf [0..8.39M), Wpad [8.39M..12.97M)
  bf16_t* u_bf    = arena;
  bf16_t* Wpad    = arena + (size_t)ROWS * 1024;
  // arena phase 2: prevst_bf overlays u_bf (u dead after in_proj);
  //               1024*64*128 = 8,388,608 elems = exactly u_bf size
  bf16_t* prevbf  = arena;
  // arena phase 3 (out_proj): ypre_bf overlays [0..16.77M) (prevbf dead),
  //               Wout_bf [16.77M..18.87M) written at step 0, disjoint.
  bf16_t* ypre_bf = arena;
  bf16_t* Wout_bf = arena + (size_t)ROWS * DSSM;
  float*  ypre    = zx + 2048;   // f32 overlay: zx cols 2048..4095

  // 0. casts
  {
    const long n_u = (long)ROWS * 1024;
    cast_f32_bf16<<<dim3((n_u/8 + 255)/256), 256, 0, stream>>>(u, u_bf, n_u, n_u);
    const long n_wv = (long)4384 * 1024, n_wt = (long)4480 * 1024;
    cast_f32_bf16<<<dim3((n_wt/8 + 255)/256), 256, 0, stream>>>(W_in, Wpad, n_wv, n_wt);
    const long n_wo = (long)1024 * DSSM;
    cast_f32_bf16<<<dim3((n_wo/8 + 255)/256), 256, 0, stream>>>(W_out, Wout_bf, n_wo, n_wo);
  }
  // 1. in_proj (MFMA bf16)
  gemm_bt_mfma<<<dim3(35, 64), 256, 0, stream>>>(u_bf, Wpad, zx, ROWS, 4384, 1024,
                                                 1024, 1024, ZX_LD);
  // 2. conv + silu -> bf16 xconv
  conv_silu_kernel<<<dim3(9, ROWS), 256, 0, stream>>>(zx, conv_w, conv_b, xconv);
  // 3. dt softplus
  dt_kernel<<<dim3((ROWS * NH) / 256), 256, 0, stream>>>(zx, dt_bias, dtv);
  // 4. per-chunk cumsum + states
  chunk_states_kernel<<<dim3(1024), 256, 0, stream>>>(dtv, A_log, xconv, acsb, totals, states);
  // 5. inter-chunk scan -> bf16 prev states
  chunk_prefix_kernel<<<dim3(64), 256, 0, stream>>>(states, totals, prevbf);
  // 6. intra-chunk Y via MFMA -> ypre f32 overlay
  y_kernel_mfma<<<dim3(4096), 256, 0, stream>>>(xconv, dtv, acsb, prevbf, Dv, ypre, ZX_LD);
  // 7. gated rmsnorm -> bf16
  rmsnorm_gate_kernel<<<dim3(ROWS), 256, 0, stream>>>(zx, norm_w, ypre_bf);
  // 8. out_proj (MFMA bf16)
  gemm_bt_mfma<<<dim3(8, 64), 256, 0, stream>>>(ypre_bf, Wout_bf, out, ROWS, 1024, 2048,
                                                2048, 2048, 1024);
}

// Round 7
// 525.154 us; speedup vs baseline: 3.9134x; 1.1186x over previous
//
#include <hip/hip_runtime.h>
#include <hip/hip_bf16.h>

// ---- problem constants ----
#define ZX_LD   4384   // in_proj output width (z 2048 | xBC 2304 | dt 32)
#define XC_LD   2304   // conv dim (x 2048 | B 128 | C 128)
#define NH      32
#define HD      64
#define DS      128
#define CHK     256
#define NC      16
#define LTOT    4096
#define ROWS    8192   // BATCH * SEQLEN
#define DSSM    2048
#define YPAD    80     // Sl/xT row stride (bf16) in y-kernel

typedef __bf16 bf16_t;
typedef bf16_t bf16x8 __attribute__((ext_vector_type(8)));
typedef float  f32x4  __attribute__((ext_vector_type(4)));
typedef unsigned short u16x8 __attribute__((ext_vector_type(8)));
typedef unsigned short u16x4 __attribute__((ext_vector_type(4)));

__device__ inline float bf2f(unsigned short u) {
  unsigned int x = ((unsigned int)u) << 16;
  float f; __builtin_memcpy(&f, &x, 4); return f;
}

#define GLOAD_LDS16(gp, lp) \
  __builtin_amdgcn_global_load_lds((const __attribute__((address_space(1))) void*)(gp), \
                                   (__attribute__((address_space(3))) void*)(lp), 16, 0, 0)

// =====================================================================
// cast fp32 -> bf16, zero-fill past nvalid (nvalid multiple of 8)
// =====================================================================
__global__ __launch_bounds__(256) void cast_f32_bf16(
    const float* __restrict__ in, bf16_t* __restrict__ out,
    long nvalid, long total)
{
  const long e0 = ((long)blockIdx.x * 256 + threadIdx.x) * 8;
  if (e0 >= total) return;
  bf16x8 o;
  if (e0 + 8 <= nvalid) {
    const float4 a = *(const float4*)(in + e0);
    const float4 b = *(const float4*)(in + e0 + 4);
    o[0]=(bf16_t)a.x; o[1]=(bf16_t)a.y; o[2]=(bf16_t)a.z; o[3]=(bf16_t)a.w;
    o[4]=(bf16_t)b.x; o[5]=(bf16_t)b.y; o[6]=(bf16_t)b.z; o[7]=(bf16_t)b.w;
  } else {
#pragma unroll
    for (int j = 0; j < 8; ++j) o[j] = (bf16_t)0.f;
  }
  *(bf16x8*)(out + e0) = o;
}

// =====================================================================
// bf16 MFMA GEMM: C[m][n] = sum_k A[m][k]*B[n][k]  (m97-style 2-barrier)
// + XCD-bijective blockIdx swizzle (T1, m204 form)
// =====================================================================
__global__ __launch_bounds__(256) void gemm_bt_mfma(
    const bf16_t* __restrict__ A, const bf16_t* __restrict__ B,
    float* __restrict__ C, int M, int N, int K,
    int lda, int ldb, int ldc)
{
  __shared__ __align__(16) bf16_t As[128 * 32];
  __shared__ __align__(16) bf16_t Bs[128 * 32];
  const int tid  = threadIdx.x;
  const int lane = tid & 63;
  const int wave = tid >> 6;

  // XCD-aware bijective swizzle of the flattened workgroup id
  const int nwg  = gridDim.x * gridDim.y;
  int wgid = blockIdx.y * gridDim.x + blockIdx.x;
  {
    const int xcd = wgid & 7, local = wgid >> 3;
    const int q = nwg >> 3, r = nwg & 7;
    wgid = (xcd < r ? xcd * (q + 1) : r * (q + 1) + (xcd - r) * q) + local;
  }
  const int bm = (wgid / gridDim.x) * 128;
  const int bn = (wgid % gridDim.x) * 128;

  const int wr = (wave >> 1) * 64;
  const int wc = (wave & 1) * 64;

  const int c0   = wave * 2;
  const int lrow = lane >> 2;
  const int lcol = (lane & 3) * 8;
  const bf16_t* Ag0 = A + (size_t)(bm + c0 * 16 + lrow) * lda + lcol;
  const bf16_t* Ag1 = A + (size_t)(bm + c0 * 16 + 16 + lrow) * lda + lcol;
  const bf16_t* Bg0 = B + (size_t)(bn + c0 * 16 + lrow) * ldb + lcol;
  const bf16_t* Bg1 = B + (size_t)(bn + c0 * 16 + 16 + lrow) * ldb + lcol;
  bf16_t* Al0 = As + c0 * 512;
  bf16_t* Al1 = As + c0 * 512 + 512;
  bf16_t* Bl0 = Bs + c0 * 512;
  bf16_t* Bl1 = Bs + c0 * 512 + 512;

  f32x4 acc[4][4];
#pragma unroll
  for (int i = 0; i < 4; ++i)
#pragma unroll
    for (int j = 0; j < 4; ++j) acc[i][j] = (f32x4){0.f, 0.f, 0.f, 0.f};

  const int nk = K >> 5;
  for (int kt = 0; kt < nk; ++kt) {
    const int k0 = kt * 32;
    __syncthreads();
    GLOAD_LDS16(Ag0 + k0, Al0);
    GLOAD_LDS16(Ag1 + k0, Al1);
    GLOAD_LDS16(Bg0 + k0, Bl0);
    GLOAD_LDS16(Bg1 + k0, Bl1);
    __syncthreads();

    const bf16_t* Ab = As + (wr + (lane & 15)) * 32 + (lane >> 4) * 8;
    const bf16_t* Bb = Bs + (wc + (lane & 15)) * 32 + (lane >> 4) * 8;
    bf16x8 af[4], bfv[4];
#pragma unroll
    for (int mi = 0; mi < 4; ++mi) af[mi]  = *(const bf16x8*)(Ab + mi * 512);
#pragma unroll
    for (int ni = 0; ni < 4; ++ni) bfv[ni] = *(const bf16x8*)(Bb + ni * 512);
#pragma unroll
    for (int mi = 0; mi < 4; ++mi)
#pragma unroll
      for (int ni = 0; ni < 4; ++ni)
        acc[mi][ni] = __builtin_amdgcn_mfma_f32_16x16x32_bf16(af[mi], bfv[ni], acc[mi][ni], 0, 0, 0);
  }

  const int crow0 = bm + wr + (lane >> 4) * 4;
  const int ccol0 = bn + wc + (lane & 15);
#pragma unroll
  for (int ni = 0; ni < 4; ++ni) {
    const int ccol = ccol0 + ni * 16;
    if (ccol < N) {
#pragma unroll
      for (int mi = 0; mi < 4; ++mi) {
#pragma unroll
        for (int j = 0; j < 4; ++j) {
          C[(size_t)(crow0 + mi * 16 + j) * ldc + ccol] = acc[mi][ni][j];
        }
      }
    }
  }
}

// =====================================================================
// depthwise causal conv (k=4) + bias + SiLU; writes bf16 xconv
// =====================================================================
__global__ __launch_bounds__(256) void conv_silu_kernel(
    const float* __restrict__ zx, const float* __restrict__ cw,
    const float* __restrict__ cb, bf16_t* __restrict__ xconv)
{
  const int ch  = blockIdx.x * 256 + threadIdx.x;  // 0..2303
  const int row = blockIdx.y;                      // 0..8191
  const int l   = row & (LTOT - 1);
  float acc = cb[ch];
#pragma unroll
  for (int k = 0; k < 4; ++k) {
    const int ls = l - 3 + k;
    if (ls >= 0) acc = fmaf(zx[(size_t)(row - 3 + k) * ZX_LD + 2048 + ch], cw[ch*4 + k], acc);
  }
  const float r = acc / (1.f + __expf(-acc));   // silu
  xconv[(size_t)row * XC_LD + ch] = (bf16_t)r;
}

// =====================================================================
// dt = softplus(dt_raw + dt_bias)
// =====================================================================
__global__ __launch_bounds__(256) void dt_kernel(
    const float* __restrict__ zx, const float* __restrict__ dtb,
    float* __restrict__ dtv)
{
  const int idx = blockIdx.x * 256 + threadIdx.x;  // < ROWS*NH
  const int row = idx >> 5;
  const int hh  = idx & 31;
  const float x = zx[(size_t)row * ZX_LD + 4352 + hh] + dtb[hh];
  dtv[idx] = (x > 20.f) ? x : log1pf(__expf(x));
}

// =====================================================================
// per (b,c,h): cumsum(dA) within chunk; chunk totals; chunk states.
// MFMA version: states[p][n] = sum_l (x[l,p]*wdt[l]) * B[l,n]
//   A-operand: xT [p][l] (weighted, XOR-swizzled 16B chunks)
//   B-operand: Bt [n][l] (raw bits, XOR-swizzled)
// 4 subtiles of l=64; 4 waves; wave owns n-slice of 32.
// =====================================================================
__global__ __launch_bounds__(256) void chunk_states_kernel(
    const float* __restrict__ dtv, const float* __restrict__ A_log,
    const bf16_t* __restrict__ xconv,
    float* __restrict__ acs, float* __restrict__ totals,
    float* __restrict__ states)
{
  const int bid = blockIdx.x;          // ((b*16+c)*32+h)
  const int h = bid & 31;
  const int c = (bid >> 5) & 15;
  const int b = bid >> 9;
  const int rowbase = b * LTOT + c * CHK;
  const int tid = threadIdx.x;
  const int lane = tid & 63;
  const int wv   = tid >> 6;
  const int ln15 = lane & 15;
  const int lg   = lane >> 4;

  __shared__ float sWdt[256];
  __shared__ float wsum[4];
  __shared__ __align__(16) bf16_t xT[64 * 64];    // [p][l] swizzled
  __shared__ __align__(16) bf16_t Bt[128 * 64];   // [n][l] swizzled
  unsigned short* Btu = (unsigned short*)Bt;

  // ---- inclusive scan of dA over the chunk ----
  const float dt = dtv[(size_t)(rowbase + tid) * NH + h];
  const float Ah = -__expf(A_log[h]);
  float v = dt * Ah;
#pragma unroll
  for (int off = 1; off < 64; off <<= 1) {
    float up = __shfl_up(v, off, 64);
    if ((tid & 63) >= off) v += up;
  }
  if ((tid & 63) == 63) wsum[tid >> 6] = v;
  __syncthreads();
  const float w0 = wsum[0], w1 = wsum[1], w2 = wsum[2], w3 = wsum[3];
  float base = 0.f;
  if (wv > 0) base += w0;
  if (wv > 1) base += w1;
  if (wv > 2) base += w2;
  const float acsl  = v + base;
  const float total = w0 + w1 + w2 + w3;
  acs[bid * 256 + tid] = acsl;
  if (tid == 0) totals[(b * 32 + h) * 16 + c] = total;
  sWdt[tid] = __expf(total - acsl) * dt;

  f32x4 acc[4][2];
#pragma unroll
  for (int i = 0; i < 4; ++i)
#pragma unroll
    for (int j = 0; j < 2; ++j) acc[i][j] = (f32x4){0.f, 0.f, 0.f, 0.f};

  const int s  = tid >> 2;          // l-local row this thread stages
  const int p0 = (tid & 3) * 16;    // x cols
  const int n0 = (tid & 3) * 32;    // B cols

  for (int ls = 0; ls < 4; ++ls) {
    const int l0 = ls * 64;
    __syncthreads();   // prior MFMA reads done; sWdt visible (1st iter)
    {
      const float wgt = sWdt[l0 + s];
      const bf16_t* xr = xconv + (size_t)(rowbase + l0 + s) * XC_LD + h * HD + p0;
      u16x8 v0 = *(const u16x8*)xr;
      u16x8 v1 = *(const u16x8*)(xr + 8);
#pragma unroll
      for (int j = 0; j < 8; ++j) {
        const int p = p0 + j;
        xT[p * 64 + ((((s >> 3) ^ (p & 7)) << 3) | (s & 7))] = (bf16_t)(bf2f(v0[j]) * wgt);
      }
#pragma unroll
      for (int j = 0; j < 8; ++j) {
        const int p = p0 + 8 + j;
        xT[p * 64 + ((((s >> 3) ^ (p & 7)) << 3) | (s & 7))] = (bf16_t)(bf2f(v1[j]) * wgt);
      }
      const bf16_t* br = xconv + (size_t)(rowbase + l0 + s) * XC_LD + 2048 + n0;
#pragma unroll
      for (int q = 0; q < 4; ++q) {
        u16x8 t = *(const u16x8*)(br + q * 8);
#pragma unroll
        for (int j = 0; j < 8; ++j) {
          const int n = n0 + q * 8 + j;
          Btu[n * 64 + ((((s >> 3) ^ (n & 7)) << 3) | (s & 7))] = t[j];
        }
      }
    }
    __syncthreads();
    // MFMA: k=64 (2 ksteps of 32)
#pragma unroll
    for (int ks = 0; ks < 2; ++ks) {
      bf16x8 af[4];
#pragma unroll
      for (int mi = 0; mi < 4; ++mi) {
        const int row = mi * 16 + ln15;
        const int chunk = (ks * 4 + lg) ^ (row & 7);
        af[mi] = *(const bf16x8*)(xT + row * 64 + chunk * 8);
      }
#pragma unroll
      for (int ni = 0; ni < 2; ++ni) {
        const int nrow = wv * 32 + ni * 16 + ln15;
        const int chunk = (ks * 4 + lg) ^ (nrow & 7);
        bf16x8 bfr = *(const bf16x8*)(Bt + nrow * 64 + chunk * 8);
#pragma unroll
        for (int mi = 0; mi < 4; ++mi)
          acc[mi][ni] = __builtin_amdgcn_mfma_f32_16x16x32_bf16(af[mi], bfr, acc[mi][ni], 0, 0, 0);
      }
    }
  }

  // epilogue: D layout col=lane&15, row=(lane>>4)*4+j
  const size_t sbase = (size_t)bid * (HD * DS);
#pragma unroll
  for (int mi = 0; mi < 4; ++mi) {
#pragma unroll
    for (int ni = 0; ni < 2; ++ni) {
      const int n = wv * 32 + ni * 16 + ln15;
#pragma unroll
      for (int j = 0; j < 4; ++j) {
        const int p = mi * 16 + lg * 4 + j;
        states[sbase + p * DS + n] = acc[mi][ni][j];
      }
    }
  }
}

// =====================================================================
// inter-chunk scan: grid (64 bh, 32 e-groups); one state element/thread.
// prev-state written as BF16 to prevbf; states untouched.
// =====================================================================
__global__ __launch_bounds__(256) void chunk_prefix_kernel(
    const float* __restrict__ st, const float* __restrict__ totals,
    bf16_t* __restrict__ prevbf)
{
  const int bh = blockIdx.x;   // b*32+h
  const int b = bh >> 5;
  const int h = bh & 31;
  const int e = blockIdx.y;    // 0..31
  const int tid = threadIdx.x;
  float P = 0.f;
  for (int c = 0; c < NC; ++c) {
    const size_t idx = (size_t)((b * 16 + c) * 32 + h) * (HD * DS) + e * 256 + tid;
    const float g = __expf(totals[bh * 16 + c]);
    prevbf[idx] = (bf16_t)P;
    P = fmaf(P, g, st[idx]);
  }
}

// =====================================================================
// Y kernel, MFMA version
// =====================================================================
__global__ __launch_bounds__(256) void y_kernel_mfma(
    const bf16_t* __restrict__ xconv, const float* __restrict__ dtv,
    const float* __restrict__ acs,   const bf16_t* __restrict__ prevbf,
    const float* __restrict__ Dv,    float* __restrict__ ypre, int ypld)
{
  const int bid = blockIdx.x;            // (((b*16+c)*32+h)*4+lt)
  const int lt = bid & 3;
  const int h  = (bid >> 2) & 31;
  const int c  = (bid >> 7) & 15;
  const int b  = bid >> 11;
  const int bch = (b * 16 + c) * 32 + h;
  const int rowbase = b * LTOT + c * CHK;
  const int tid  = threadIdx.x;
  const int lane = tid & 63;
  const int wv   = tid >> 6;
  const int ln15 = lane & 15;
  const int lg   = lane >> 4;

  __shared__ float sAcs[256];
  __shared__ float sDt[256];
  __shared__ __align__(16) bf16_t Cl[64 * 128];
  __shared__ __align__(16) bf16_t Bl[64 * 128];
  __shared__ __align__(16) bf16_t Sl[64 * YPAD];
  __shared__ __align__(16) bf16_t xT[64 * YPAD];
  unsigned short* xTu = (unsigned short*)xT;

  sAcs[tid] = acs[bch * 256 + tid];
  sDt[tid]  = dtv[(size_t)(rowbase + tid) * NH + h];

#pragma unroll
  for (int i = 0; i < 4; ++i) {
    const int chunk = wv * 4 + i;
    const int r  = chunk * 4 + lg;
    const int cs = ln15 ^ (r & 7);
    const bf16_t* src = xconv + (size_t)(rowbase + lt*64 + r) * XC_LD + 2176 + cs * 8;
    GLOAD_LDS16(src, Cl + chunk * 512);
  }
  __syncthreads();

  bf16x8 cf[4][4];
#pragma unroll
  for (int mi = 0; mi < 4; ++mi) {
    const int row = mi * 16 + ln15;
#pragma unroll
    for (int ks = 0; ks < 4; ++ks) {
      const int chunk = (ks * 4 + lg) ^ (row & 7);
      cf[mi][ks] = *(const bf16x8*)(Cl + row * 128 + chunk * 8);
    }
  }

  f32x4 acc[4];
#pragma unroll
  for (int mi = 0; mi < 4; ++mi) acc[mi] = (f32x4){0.f, 0.f, 0.f, 0.f};
  {
    const bf16_t* pb = prevbf + ((size_t)bch * 64 + 16 * wv + ln15) * 128 + lg * 8;
#pragma unroll
    for (int ks = 0; ks < 4; ++ks) {
      bf16x8 pf = *(const bf16x8*)(pb + ks * 32);
#pragma unroll
      for (int mi = 0; mi < 4; ++mi)
        acc[mi] = __builtin_amdgcn_mfma_f32_16x16x32_bf16(cf[mi][ks], pf, acc[mi], 0, 0, 0);
    }
  }
#pragma unroll
  for (int mi = 0; mi < 4; ++mi) {
#pragma unroll
    for (int j = 0; j < 4; ++j)
      acc[mi][j] *= __expf(sAcs[lt*64 + mi*16 + lg*4 + j]);
  }

  for (int st = 0; st <= lt; ++st) {
    __syncthreads();
#pragma unroll
    for (int i = 0; i < 4; ++i) {
      const int chunk = wv * 4 + i;
      const int r  = chunk * 4 + lg;
      const int cs = ln15 ^ (r & 7);
      const bf16_t* src = xconv + (size_t)(rowbase + st*64 + r) * XC_LD + 2048 + cs * 8;
      GLOAD_LDS16(src, Bl + chunk * 512);
    }
    {
      const int s  = tid >> 2;
      const int p0 = (tid & 3) * 16;
      const bf16_t* xr = xconv + (size_t)(rowbase + st*64 + s) * XC_LD + h * HD + p0;
      u16x8 v0 = *(const u16x8*)xr;
      u16x8 v1 = *(const u16x8*)(xr + 8);
#pragma unroll
      for (int j = 0; j < 8; ++j) xTu[(p0 + j) * YPAD + s] = v0[j];
#pragma unroll
      for (int j = 0; j < 8; ++j) xTu[(p0 + 8 + j) * YPAD + s] = v1[j];
    }
    __syncthreads();

    f32x4 sa[4];
#pragma unroll
    for (int mi = 0; mi < 4; ++mi) sa[mi] = (f32x4){0.f, 0.f, 0.f, 0.f};
    {
      const int row = 16 * wv + ln15;
#pragma unroll
      for (int ks = 0; ks < 4; ++ks) {
        const int chunk = (ks * 4 + lg) ^ (row & 7);
        bf16x8 bfr = *(const bf16x8*)(Bl + row * 128 + chunk * 8);
#pragma unroll
        for (int mi = 0; mi < 4; ++mi)
          sa[mi] = __builtin_amdgcn_mfma_f32_16x16x32_bf16(cf[mi][ks], bfr, sa[mi], 0, 0, 0);
      }
    }
    {
      const int sg = st * 64 + 16 * wv + ln15;
      const float as  = sAcs[sg];
      const float dts = sDt[sg];
#pragma unroll
      for (int mi = 0; mi < 4; ++mi) {
#pragma unroll
        for (int j = 0; j < 4; ++j) {
          const int lloc = mi * 16 + lg * 4 + j;
          const int ll = lt * 64 + lloc;
          float wvv = 0.f;
          if (ll >= sg) wvv = sa[mi][j] * __expf(sAcs[ll] - as) * dts;
          Sl[lloc * YPAD + 16 * wv + ln15] = (bf16_t)wvv;
        }
      }
    }
    __syncthreads();

#pragma unroll
    for (int ks2 = 0; ks2 < 2; ++ks2) {
      bf16x8 xf = *(const bf16x8*)(xT + (16 * wv + ln15) * YPAD + ks2 * 32 + lg * 8);
#pragma unroll
      for (int mi = 0; mi < 4; ++mi) {
        bf16x8 sf = *(const bf16x8*)(Sl + (mi * 16 + ln15) * YPAD + ks2 * 32 + lg * 8);
        acc[mi] = __builtin_amdgcn_mfma_f32_16x16x32_bf16(sf, xf, acc[mi], 0, 0, 0);
      }
    }
  }

  const float Dh = Dv[h];
  const int p = 16 * wv + ln15;
#pragma unroll
  for (int mi = 0; mi < 4; ++mi) {
#pragma unroll
    for (int j = 0; j < 4; ++j) {
      const int lloc = mi * 16 + lg * 4 + j;
      const int row  = rowbase + lt * 64 + lloc;
      const float xv = (float)xT[p * YPAD + lloc];
      ypre[(size_t)row * ypld + h * HD + p] = acc[mi][j] + xv * Dh;
    }
  }
}

// =====================================================================
// gated RMSNorm: read ypre f32 overlay + z, write bf16 ypre_bf
// =====================================================================
__global__ __launch_bounds__(256) void rmsnorm_gate_kernel(
    const float* __restrict__ zx, const float* __restrict__ normw,
    bf16_t* __restrict__ ypre_bf)
{
  const int row = blockIdx.x;
  const int tid = threadIdx.x;
  float vals[8];
  float ss = 0.f;
#pragma unroll
  for (int e = 0; e < 8; ++e) {
    const int col = e * 256 + tid;
    const float y = zx[(size_t)row * ZX_LD + 2048 + col];
    const float z = zx[(size_t)row * ZX_LD + col];
    const float sz = z / (1.f + __expf(-z));
    const float v = y * sz;
    vals[e] = v;
    ss += v * v;
  }
#pragma unroll
  for (int off = 32; off >= 1; off >>= 1) ss += __shfl_xor(ss, off, 64);
  __shared__ float red[4];
  if ((tid & 63) == 0) red[tid >> 6] = ss;
  __syncthreads();
  const float tot = red[0] + red[1] + red[2] + red[3];
  const float scale = rsqrtf(tot / (float)DSSM + 1e-5f);
#pragma unroll
  for (int e = 0; e < 8; ++e) {
    const int col = e * 256 + tid;
    ypre_bf[(size_t)row * DSSM + col] = (bf16_t)(vals[e] * scale * normw[col]);
  }
}

// =====================================================================
extern "C" void kernel_launch(void* const* d_in, const int* in_sizes, int n_in,
                              void* d_out, int out_size, void* d_ws, size_t ws_size,
                              hipStream_t stream)
{
  const float* u       = (const float*)d_in[0];
  const float* W_in    = (const float*)d_in[1];
  const float* conv_w  = (const float*)d_in[2];
  const float* conv_b  = (const float*)d_in[3];
  const float* dt_bias = (const float*)d_in[4];
  const float* A_log   = (const float*)d_in[5];
  const float* Dv      = (const float*)d_in[6];
  const float* norm_w  = (const float*)d_in[7];
  const float* W_out   = (const float*)d_in[8];
  float* out = (float*)d_out;

  // ---- workspace layout (byte offsets), total 254,808,064 B = 243.0 MiB ----
  const size_t OFF_XC  = (size_t)ROWS * ZX_LD * 4;
  const size_t OFF_DT  = OFF_XC  + (size_t)ROWS * XC_LD * 2;
  const size_t OFF_ACS = OFF_DT  + (size_t)ROWS * NH * 4;
  const size_t OFF_TOT = OFF_ACS + (size_t)1024 * 256 * 4;
  const size_t OFF_ST  = OFF_TOT + 4096;
  const size_t OFF_AR  = OFF_ST  + (size_t)1024 * HD * DS * 4;
  const size_t need    = OFF_AR  + (size_t)ROWS * XC_LD * 2;
  if (ws_size < need) return;

  char* w = (char*)d_ws;
  float*  zx      = (float*)w;
  bf16_t* xconv   = (bf16_t*)(w + OFF_XC);
  float*  dtv     = (float*)(w + OFF_DT);
  float*  acsb    = (float*)(w + OFF_ACS);
  float*  totals  = (float*)(w + OFF_TOT);
  float*  states  = (float*)(w + OFF_ST);
  bf16_t* arena   = (bf16_t*)(w + OFF_AR);
  bf16_t* u_bf    = arena;
  bf16_t* Wpad    = arena + (size_t)ROWS * 1024;
  bf16_t* prevbf  = arena;                      // overlays u_bf (dead)
  bf16_t* ypre_bf = arena;                      // overlays prevbf (dead)
  bf16_t* Wout_bf = arena + (size_t)ROWS * DSSM;
  float*  ypre    = zx + 2048;                  // f32 overlay in zx

  // 0. casts
  {
    const long n_u = (long)ROWS * 1024;
    cast_f32_bf16<<<dim3((n_u/8 + 255)/256), 256, 0, stream>>>(u, u_bf, n_u, n_u);
    const long n_wv = (long)4384 * 1024, n_wt = (long)4480 * 1024;
    cast_f32_bf16<<<dim3((n_wt/8 + 255)/256), 256, 0, stream>>>(W_in, Wpad, n_wv, n_wt);
    const long n_wo = (long)1024 * DSSM;
    cast_f32_bf16<<<dim3((n_wo/8 + 255)/256), 256, 0, stream>>>(W_out, Wout_bf, n_wo, n_wo);
  }
  // 1. in_proj (MFMA bf16, XCD swizzle)
  gemm_bt_mfma<<<dim3(35, 64), 256, 0, stream>>>(u_bf, Wpad, zx, ROWS, 4384, 1024,
                                                 1024, 1024, ZX_LD);
  // 2. conv + silu -> bf16 xconv
  conv_silu_kernel<<<dim3(9, ROWS), 256, 0, stream>>>(zx, conv_w, conv_b, xconv);
  // 3. dt softplus
  dt_kernel<<<dim3((ROWS * NH) / 256), 256, 0, stream>>>(zx, dt_bias, dtv);
  // 4. per-chunk cumsum + states (MFMA)
  chunk_states_kernel<<<dim3(1024), 256, 0, stream>>>(dtv, A_log, xconv, acsb, totals, states);
  // 5. inter-chunk scan -> bf16 prev states (parallel over 32 e-groups)
  chunk_prefix_kernel<<<dim3(64, 32), 256, 0, stream>>>(states, totals, prevbf);
  // 6. intra-chunk Y via MFMA -> ypre f32 overlay
  y_kernel_mfma<<<dim3(4096), 256, 0, stream>>>(xconv, dtv, acsb, prevbf, Dv, ypre, ZX_LD);
  // 7. gated rmsnorm -> bf16
  rmsnorm_gate_kernel<<<dim3(ROWS), 256, 0, stream>>>(zx, norm_w, ypre_bf);
  // 8. out_proj (MFMA bf16, XCD swizzle)
  gemm_bt_mfma<<<dim3(8, 64), 256, 0, stream>>>(ypre_bf, Wout_bf, out, ROWS, 1024, 2048,
                                                2048, 2048, 1024);
}

// Round 8
// 508.334 us; speedup vs baseline: 4.0429x; 1.0331x over previous
//
#include <hip/hip_runtime.h>
#include <hip/hip_bf16.h>

// ---- problem constants ----
#define ZX_LD   4384   // in_proj output width (z 2048 | xBC 2304 | dt 32)
#define XC_LD   2304   // conv dim (x 2048 | B 128 | C 128)
#define NH      32
#define HD      64
#define DS      128
#define CHK     256
#define NC      16
#define LTOT    4096
#define ROWS    8192   // BATCH * SEQLEN
#define DSSM    2048
#define YPAD    80     // Sl/xT row stride (bf16) in y-kernel

typedef __bf16 bf16_t;
typedef bf16_t bf16x8 __attribute__((ext_vector_type(8)));
typedef float  f32x4  __attribute__((ext_vector_type(4)));
typedef unsigned short u16x8 __attribute__((ext_vector_type(8)));

__device__ inline float bf2f(unsigned short u) {
  unsigned int x = ((unsigned int)u) << 16;
  float f; __builtin_memcpy(&f, &x, 4); return f;
}

#define GLOAD_LDS16(gp, lp) \
  __builtin_amdgcn_global_load_lds((const __attribute__((address_space(1))) void*)(gp), \
                                   (__attribute__((address_space(3))) void*)(lp), 16, 0, 0)

// =====================================================================
// cast fp32 -> bf16, zero-fill past nvalid (nvalid multiple of 8)
// =====================================================================
__global__ __launch_bounds__(256) void cast_f32_bf16(
    const float* __restrict__ in, bf16_t* __restrict__ out,
    long nvalid, long total)
{
  const long e0 = ((long)blockIdx.x * 256 + threadIdx.x) * 8;
  if (e0 >= total) return;
  bf16x8 o;
  if (e0 + 8 <= nvalid) {
    const float4 a = *(const float4*)(in + e0);
    const float4 b = *(const float4*)(in + e0 + 4);
    o[0]=(bf16_t)a.x; o[1]=(bf16_t)a.y; o[2]=(bf16_t)a.z; o[3]=(bf16_t)a.w;
    o[4]=(bf16_t)b.x; o[5]=(bf16_t)b.y; o[6]=(bf16_t)b.z; o[7]=(bf16_t)b.w;
  } else {
#pragma unroll
    for (int j = 0; j < 8; ++j) o[j] = (bf16_t)0.f;
  }
  *(bf16x8*)(out + e0) = o;
}

// =====================================================================
// bf16 MFMA GEMM: C[m][n] = sum_k A[m][k]*B[n][k]  (m97-style 2-barrier)
// + XCD-bijective blockIdx swizzle (T1). BF16OUT selects C dtype.
// =====================================================================
template<bool BF16OUT>
__global__ __launch_bounds__(256) void gemm_bt_mfma(
    const bf16_t* __restrict__ A, const bf16_t* __restrict__ B,
    void* __restrict__ Cv, int M, int N, int K,
    int lda, int ldb, int ldc)
{
  __shared__ __align__(16) bf16_t As[128 * 32];
  __shared__ __align__(16) bf16_t Bs[128 * 32];
  const int tid  = threadIdx.x;
  const int lane = tid & 63;
  const int wave = tid >> 6;

  // XCD-aware bijective swizzle of the flattened workgroup id
  const int nwg  = gridDim.x * gridDim.y;
  int wgid = blockIdx.y * gridDim.x + blockIdx.x;
  {
    const int xcd = wgid & 7, local = wgid >> 3;
    const int q = nwg >> 3, r = nwg & 7;
    wgid = (xcd < r ? xcd * (q + 1) : r * (q + 1) + (xcd - r) * q) + local;
  }
  const int bm = (wgid / gridDim.x) * 128;
  const int bn = (wgid % gridDim.x) * 128;

  const int wr = (wave >> 1) * 64;
  const int wc = (wave & 1) * 64;

  const int c0   = wave * 2;
  const int lrow = lane >> 2;
  const int lcol = (lane & 3) * 8;
  const bf16_t* Ag0 = A + (size_t)(bm + c0 * 16 + lrow) * lda + lcol;
  const bf16_t* Ag1 = A + (size_t)(bm + c0 * 16 + 16 + lrow) * lda + lcol;
  const bf16_t* Bg0 = B + (size_t)(bn + c0 * 16 + lrow) * ldb + lcol;
  const bf16_t* Bg1 = B + (size_t)(bn + c0 * 16 + 16 + lrow) * ldb + lcol;
  bf16_t* Al0 = As + c0 * 512;
  bf16_t* Al1 = As + c0 * 512 + 512;
  bf16_t* Bl0 = Bs + c0 * 512;
  bf16_t* Bl1 = Bs + c0 * 512 + 512;

  f32x4 acc[4][4];
#pragma unroll
  for (int i = 0; i < 4; ++i)
#pragma unroll
    for (int j = 0; j < 4; ++j) acc[i][j] = (f32x4){0.f, 0.f, 0.f, 0.f};

  const int nk = K >> 5;
  for (int kt = 0; kt < nk; ++kt) {
    const int k0 = kt * 32;
    __syncthreads();
    GLOAD_LDS16(Ag0 + k0, Al0);
    GLOAD_LDS16(Ag1 + k0, Al1);
    GLOAD_LDS16(Bg0 + k0, Bl0);
    GLOAD_LDS16(Bg1 + k0, Bl1);
    __syncthreads();

    const bf16_t* Ab = As + (wr + (lane & 15)) * 32 + (lane >> 4) * 8;
    const bf16_t* Bb = Bs + (wc + (lane & 15)) * 32 + (lane >> 4) * 8;
    bf16x8 af[4], bfv[4];
#pragma unroll
    for (int mi = 0; mi < 4; ++mi) af[mi]  = *(const bf16x8*)(Ab + mi * 512);
#pragma unroll
    for (int ni = 0; ni < 4; ++ni) bfv[ni] = *(const bf16x8*)(Bb + ni * 512);
#pragma unroll
    for (int mi = 0; mi < 4; ++mi)
#pragma unroll
      for (int ni = 0; ni < 4; ++ni)
        acc[mi][ni] = __builtin_amdgcn_mfma_f32_16x16x32_bf16(af[mi], bfv[ni], acc[mi][ni], 0, 0, 0);
  }

  const int crow0 = bm + wr + (lane >> 4) * 4;
  const int ccol0 = bn + wc + (lane & 15);
#pragma unroll
  for (int ni = 0; ni < 4; ++ni) {
    const int ccol = ccol0 + ni * 16;
    if (ccol < N) {
#pragma unroll
      for (int mi = 0; mi < 4; ++mi) {
#pragma unroll
        for (int j = 0; j < 4; ++j) {
          if constexpr (BF16OUT) {
            ((bf16_t*)Cv)[(size_t)(crow0 + mi * 16 + j) * ldc + ccol] = (bf16_t)acc[mi][ni][j];
          } else {
            ((float*)Cv)[(size_t)(crow0 + mi * 16 + j) * ldc + ccol] = acc[mi][ni][j];
          }
        }
      }
    }
  }
}

// =====================================================================
// depthwise causal conv (k=4) + bias + SiLU; bf16 zx -> bf16 xconv
// =====================================================================
__global__ __launch_bounds__(256) void conv_silu_kernel(
    const bf16_t* __restrict__ zx, const float* __restrict__ cw,
    const float* __restrict__ cb, bf16_t* __restrict__ xconv)
{
  const int ch  = blockIdx.x * 256 + threadIdx.x;  // 0..2303
  const int row = blockIdx.y;                      // 0..8191
  const int l   = row & (LTOT - 1);
  float acc = cb[ch];
#pragma unroll
  for (int k = 0; k < 4; ++k) {
    const int ls = l - 3 + k;
    if (ls >= 0)
      acc = fmaf((float)zx[(size_t)(row - 3 + k) * ZX_LD + 2048 + ch], cw[ch*4 + k], acc);
  }
  const float r = acc / (1.f + __expf(-acc));   // silu
  xconv[(size_t)row * XC_LD + ch] = (bf16_t)r;
}

// =====================================================================
// dt = softplus(dt_raw + dt_bias)
// =====================================================================
__global__ __launch_bounds__(256) void dt_kernel(
    const bf16_t* __restrict__ zx, const float* __restrict__ dtb,
    float* __restrict__ dtv)
{
  const int idx = blockIdx.x * 256 + threadIdx.x;  // < ROWS*NH
  const int row = idx >> 5;
  const int hh  = idx & 31;
  const float x = (float)zx[(size_t)row * ZX_LD + 4352 + hh] + dtb[hh];
  dtv[idx] = (x > 20.f) ? x : log1pf(__expf(x));
}

// =====================================================================
// per (b,c,h): cumsum(dA) within chunk; chunk totals; chunk states.
// MFMA: states[p][n] = sum_l (x[l,p]*wdt[l]) * B[l,n]  (unchanged, proven)
// =====================================================================
__global__ __launch_bounds__(256) void chunk_states_kernel(
    const float* __restrict__ dtv, const float* __restrict__ A_log,
    const bf16_t* __restrict__ xconv,
    float* __restrict__ acs, float* __restrict__ totals,
    float* __restrict__ states)
{
  const int bid = blockIdx.x;          // ((b*16+c)*32+h)
  const int h = bid & 31;
  const int c = (bid >> 5) & 15;
  const int b = bid >> 9;
  const int rowbase = b * LTOT + c * CHK;
  const int tid = threadIdx.x;
  const int lane = tid & 63;
  const int wv   = tid >> 6;
  const int ln15 = lane & 15;
  const int lg   = lane >> 4;

  __shared__ float sWdt[256];
  __shared__ float wsum[4];
  __shared__ __align__(16) bf16_t xT[64 * 64];    // [p][l] swizzled
  __shared__ __align__(16) bf16_t Bt[128 * 64];   // [n][l] swizzled
  unsigned short* Btu = (unsigned short*)Bt;

  const float dt = dtv[(size_t)(rowbase + tid) * NH + h];
  const float Ah = -__expf(A_log[h]);
  float v = dt * Ah;
#pragma unroll
  for (int off = 1; off < 64; off <<= 1) {
    float up = __shfl_up(v, off, 64);
    if ((tid & 63) >= off) v += up;
  }
  if ((tid & 63) == 63) wsum[tid >> 6] = v;
  __syncthreads();
  const float w0 = wsum[0], w1 = wsum[1], w2 = wsum[2], w3 = wsum[3];
  float base = 0.f;
  if (wv > 0) base += w0;
  if (wv > 1) base += w1;
  if (wv > 2) base += w2;
  const float acsl  = v + base;
  const float total = w0 + w1 + w2 + w3;
  acs[bid * 256 + tid] = acsl;
  if (tid == 0) totals[(b * 32 + h) * 16 + c] = total;
  sWdt[tid] = __expf(total - acsl) * dt;

  f32x4 acc[4][2];
#pragma unroll
  for (int i = 0; i < 4; ++i)
#pragma unroll
    for (int j = 0; j < 2; ++j) acc[i][j] = (f32x4){0.f, 0.f, 0.f, 0.f};

  const int s  = tid >> 2;
  const int p0 = (tid & 3) * 16;
  const int n0 = (tid & 3) * 32;

  for (int ls = 0; ls < 4; ++ls) {
    const int l0 = ls * 64;
    __syncthreads();
    {
      const float wgt = sWdt[l0 + s];
      const bf16_t* xr = xconv + (size_t)(rowbase + l0 + s) * XC_LD + h * HD + p0;
      u16x8 v0 = *(const u16x8*)xr;
      u16x8 v1 = *(const u16x8*)(xr + 8);
#pragma unroll
      for (int j = 0; j < 8; ++j) {
        const int p = p0 + j;
        xT[p * 64 + ((((s >> 3) ^ (p & 7)) << 3) | (s & 7))] = (bf16_t)(bf2f(v0[j]) * wgt);
      }
#pragma unroll
      for (int j = 0; j < 8; ++j) {
        const int p = p0 + 8 + j;
        xT[p * 64 + ((((s >> 3) ^ (p & 7)) << 3) | (s & 7))] = (bf16_t)(bf2f(v1[j]) * wgt);
      }
      const bf16_t* br = xconv + (size_t)(rowbase + l0 + s) * XC_LD + 2048 + n0;
#pragma unroll
      for (int q = 0; q < 4; ++q) {
        u16x8 t = *(const u16x8*)(br + q * 8);
#pragma unroll
        for (int j = 0; j < 8; ++j) {
          const int n = n0 + q * 8 + j;
          Btu[n * 64 + ((((s >> 3) ^ (n & 7)) << 3) | (s & 7))] = t[j];
        }
      }
    }
    __syncthreads();
#pragma unroll
    for (int ks = 0; ks < 2; ++ks) {
      bf16x8 af[4];
#pragma unroll
      for (int mi = 0; mi < 4; ++mi) {
        const int row = mi * 16 + ln15;
        const int chunk = (ks * 4 + lg) ^ (row & 7);
        af[mi] = *(const bf16x8*)(xT + row * 64 + chunk * 8);
      }
#pragma unroll
      for (int ni = 0; ni < 2; ++ni) {
        const int nrow = wv * 32 + ni * 16 + ln15;
        const int chunk = (ks * 4 + lg) ^ (nrow & 7);
        bf16x8 bfr = *(const bf16x8*)(Bt + nrow * 64 + chunk * 8);
#pragma unroll
        for (int mi = 0; mi < 4; ++mi)
          acc[mi][ni] = __builtin_amdgcn_mfma_f32_16x16x32_bf16(af[mi], bfr, acc[mi][ni], 0, 0, 0);
      }
    }
  }

  const size_t sbase = (size_t)bid * (HD * DS);
#pragma unroll
  for (int mi = 0; mi < 4; ++mi) {
#pragma unroll
    for (int ni = 0; ni < 2; ++ni) {
      const int n = wv * 32 + ni * 16 + ln15;
#pragma unroll
      for (int j = 0; j < 4; ++j) {
        const int p = mi * 16 + lg * 4 + j;
        states[sbase + p * DS + n] = acc[mi][ni][j];
      }
    }
  }
}

// =====================================================================
// inter-chunk scan: grid (64 bh, 32 e-groups); prev-state -> bf16 prevbf
// =====================================================================
__global__ __launch_bounds__(256) void chunk_prefix_kernel(
    const float* __restrict__ st, const float* __restrict__ totals,
    bf16_t* __restrict__ prevbf)
{
  const int bh = blockIdx.x;   // b*32+h
  const int b = bh >> 5;
  const int h = bh & 31;
  const int e = blockIdx.y;    // 0..31
  const int tid = threadIdx.x;
  float P = 0.f;
  for (int c = 0; c < NC; ++c) {
    const size_t idx = (size_t)((b * 16 + c) * 32 + h) * (HD * DS) + e * 256 + tid;
    const float g = __expf(totals[bh * 16 + c]);
    prevbf[idx] = (bf16_t)P;
    P = fmaf(P, g, st[idx]);
  }
}

// =====================================================================
// Y kernel, MFMA. C/B frags loaded DIRECTLY from global (read-once,
// L2-hot — shared across 32 heads); LDS only for Sl/xT (22.5 KB ->
// 7 blocks/CU). Output written bf16 into the zx overlay.
// =====================================================================
__global__ __launch_bounds__(256) void y_kernel_mfma(
    const bf16_t* __restrict__ xconv, const float* __restrict__ dtv,
    const float* __restrict__ acs,   const bf16_t* __restrict__ prevbf,
    const float* __restrict__ Dv,    bf16_t* __restrict__ ypre, int ypld)
{
  const int bid = blockIdx.x;            // (((b*16+c)*32+h)*4+lt)
  const int lt = bid & 3;
  const int h  = (bid >> 2) & 31;
  const int c  = (bid >> 7) & 15;
  const int b  = bid >> 11;
  const int bch = (b * 16 + c) * 32 + h;
  const int rowbase = b * LTOT + c * CHK;
  const int tid  = threadIdx.x;
  const int lane = tid & 63;
  const int wv   = tid >> 6;
  const int ln15 = lane & 15;
  const int lg   = lane >> 4;

  __shared__ float sAcs[256];
  __shared__ float sDt[256];
  __shared__ __align__(16) bf16_t Sl[64 * YPAD];
  __shared__ __align__(16) bf16_t xT[64 * YPAD];
  unsigned short* xTu = (unsigned short*)xT;

  sAcs[tid] = acs[bch * 256 + tid];
  sDt[tid]  = dtv[(size_t)(rowbase + tid) * NH + h];
  __syncthreads();

  // ---- C A-frags direct from global: row = lt*64 + mi*16 + ln15 ----
  bf16x8 cf[4][4];
#pragma unroll
  for (int mi = 0; mi < 4; ++mi) {
    const bf16_t* crow = xconv + (size_t)(rowbase + lt*64 + mi*16 + ln15) * XC_LD + 2176 + lg * 8;
#pragma unroll
    for (int ks = 0; ks < 4; ++ks) cf[mi][ks] = *(const bf16x8*)(crow + ks * 32);
  }

  // ---- CP term ----
  f32x4 acc[4];
#pragma unroll
  for (int mi = 0; mi < 4; ++mi) acc[mi] = (f32x4){0.f, 0.f, 0.f, 0.f};
  {
    const bf16_t* pb = prevbf + ((size_t)bch * 64 + 16 * wv + ln15) * 128 + lg * 8;
#pragma unroll
    for (int ks = 0; ks < 4; ++ks) {
      bf16x8 pf = *(const bf16x8*)(pb + ks * 32);
#pragma unroll
      for (int mi = 0; mi < 4; ++mi)
        acc[mi] = __builtin_amdgcn_mfma_f32_16x16x32_bf16(cf[mi][ks], pf, acc[mi], 0, 0, 0);
    }
  }
#pragma unroll
  for (int mi = 0; mi < 4; ++mi) {
#pragma unroll
    for (int j = 0; j < 4; ++j)
      acc[mi][j] *= __expf(sAcs[lt*64 + mi*16 + lg*4 + j]);
  }

  // ---- causal st loop ----
  for (int st = 0; st <= lt; ++st) {
    __syncthreads();   // prior PV done reading Sl/xT
    // stage x transposed into LDS
    {
      const int s  = tid >> 2;
      const int p0 = (tid & 3) * 16;
      const bf16_t* xr = xconv + (size_t)(rowbase + st*64 + s) * XC_LD + h * HD + p0;
      u16x8 v0 = *(const u16x8*)xr;
      u16x8 v1 = *(const u16x8*)(xr + 8);
#pragma unroll
      for (int j = 0; j < 8; ++j) xTu[(p0 + j) * YPAD + s] = v0[j];
#pragma unroll
      for (int j = 0; j < 8; ++j) xTu[(p0 + 8 + j) * YPAD + s] = v1[j];
    }

    // QK with B-frags direct from global: row = st*64 + 16*wv + ln15
    f32x4 sa[4];
#pragma unroll
    for (int mi = 0; mi < 4; ++mi) sa[mi] = (f32x4){0.f, 0.f, 0.f, 0.f};
    {
      const bf16_t* brow = xconv + (size_t)(rowbase + st*64 + 16*wv + ln15) * XC_LD + 2048 + lg * 8;
#pragma unroll
      for (int ks = 0; ks < 4; ++ks) {
        bf16x8 bfr = *(const bf16x8*)(brow + ks * 32);
#pragma unroll
        for (int mi = 0; mi < 4; ++mi)
          sa[mi] = __builtin_amdgcn_mfma_f32_16x16x32_bf16(cf[mi][ks], bfr, sa[mi], 0, 0, 0);
      }
    }
    // decay * mask * dt -> bf16 -> Sl[l][s]
    {
      const int sg = st * 64 + 16 * wv + ln15;
      const float as  = sAcs[sg];
      const float dts = sDt[sg];
#pragma unroll
      for (int mi = 0; mi < 4; ++mi) {
#pragma unroll
        for (int j = 0; j < 4; ++j) {
          const int lloc = mi * 16 + lg * 4 + j;
          const int ll = lt * 64 + lloc;
          float wvv = 0.f;
          if (ll >= sg) wvv = sa[mi][j] * __expf(sAcs[ll] - as) * dts;
          Sl[lloc * YPAD + 16 * wv + ln15] = (bf16_t)wvv;
        }
      }
    }
    __syncthreads();   // Sl/xT visible

    // PV: acc += S~ @ x
#pragma unroll
    for (int ks2 = 0; ks2 < 2; ++ks2) {
      bf16x8 xf = *(const bf16x8*)(xT + (16 * wv + ln15) * YPAD + ks2 * 32 + lg * 8);
#pragma unroll
      for (int mi = 0; mi < 4; ++mi) {
        bf16x8 sf = *(const bf16x8*)(Sl + (mi * 16 + ln15) * YPAD + ks2 * 32 + lg * 8);
        acc[mi] = __builtin_amdgcn_mfma_f32_16x16x32_bf16(sf, xf, acc[mi], 0, 0, 0);
      }
    }
  }

  // ---- epilogue: + x*D (xT holds st=lt rows), write bf16 ----
  const float Dh = Dv[h];
  const int p = 16 * wv + ln15;
#pragma unroll
  for (int mi = 0; mi < 4; ++mi) {
#pragma unroll
    for (int j = 0; j < 4; ++j) {
      const int lloc = mi * 16 + lg * 4 + j;
      const int row  = rowbase + lt * 64 + lloc;
      const float xv = (float)xT[p * YPAD + lloc];
      ypre[(size_t)row * ypld + h * HD + p] = (bf16_t)(acc[mi][j] + xv * Dh);
    }
  }
}

// =====================================================================
// gated RMSNorm: z and y both bf16 in zx; write bf16 ypre_bf (dense)
// =====================================================================
__global__ __launch_bounds__(256) void rmsnorm_gate_kernel(
    const bf16_t* __restrict__ zx, const float* __restrict__ normw,
    bf16_t* __restrict__ ypre_bf)
{
  const int row = blockIdx.x;
  const int tid = threadIdx.x;
  const unsigned short* zr = (const unsigned short*)(zx + (size_t)row * ZX_LD);
  u16x8 yv = *(const u16x8*)(zr + 2048 + tid * 8);
  u16x8 zv = *(const u16x8*)(zr + tid * 8);
  float vals[8];
  float ss = 0.f;
#pragma unroll
  for (int j = 0; j < 8; ++j) {
    const float y = bf2f(yv[j]);
    const float z = bf2f(zv[j]);
    const float sz = z / (1.f + __expf(-z));
    const float v = y * sz;
    vals[j] = v;
    ss += v * v;
  }
#pragma unroll
  for (int off = 32; off >= 1; off >>= 1) ss += __shfl_xor(ss, off, 64);
  __shared__ float red[4];
  if ((tid & 63) == 0) red[tid >> 6] = ss;
  __syncthreads();
  const float tot = red[0] + red[1] + red[2] + red[3];
  const float scale = rsqrtf(tot / (float)DSSM + 1e-5f);
  const float4 w0 = *(const float4*)(normw + tid * 8);
  const float4 w1 = *(const float4*)(normw + tid * 8 + 4);
  bf16x8 o;
  o[0] = (bf16_t)(vals[0] * scale * w0.x);
  o[1] = (bf16_t)(vals[1] * scale * w0.y);
  o[2] = (bf16_t)(vals[2] * scale * w0.z);
  o[3] = (bf16_t)(vals[3] * scale * w0.w);
  o[4] = (bf16_t)(vals[4] * scale * w1.x);
  o[5] = (bf16_t)(vals[5] * scale * w1.y);
  o[6] = (bf16_t)(vals[6] * scale * w1.z);
  o[7] = (bf16_t)(vals[7] * scale * w1.w);
  *(bf16x8*)(ypre_bf + (size_t)row * DSSM + tid * 8) = o;
}

// =====================================================================
extern "C" void kernel_launch(void* const* d_in, const int* in_sizes, int n_in,
                              void* d_out, int out_size, void* d_ws, size_t ws_size,
                              hipStream_t stream)
{
  const float* u       = (const float*)d_in[0];
  const float* W_in    = (const float*)d_in[1];
  const float* conv_w  = (const float*)d_in[2];
  const float* conv_b  = (const float*)d_in[3];
  const float* dt_bias = (const float*)d_in[4];
  const float* A_log   = (const float*)d_in[5];
  const float* Dv      = (const float*)d_in[6];
  const float* norm_w  = (const float*)d_in[7];
  const float* W_out   = (const float*)d_in[8];
  float* out = (float*)d_out;

  // ---- workspace layout (byte offsets), ~183 MiB total ----
  const size_t OFF_XC  = (size_t)ROWS * ZX_LD * 2;              // zx bf16
  const size_t OFF_DT  = OFF_XC  + (size_t)ROWS * XC_LD * 2;    // xconv bf16
  const size_t OFF_ACS = OFF_DT  + (size_t)ROWS * NH * 4;       // dtv f32
  const size_t OFF_TOT = OFF_ACS + (size_t)1024 * 256 * 4;      // acs f32
  const size_t OFF_ST  = OFF_TOT + 4096;                        // totals
  const size_t OFF_AR  = OFF_ST  + (size_t)1024 * HD * DS * 4;  // states f32
  const size_t need    = OFF_AR  + (size_t)ROWS * XC_LD * 2;    // arena bf16
  if (ws_size < need) return;

  char* w = (char*)d_ws;
  bf16_t* zxb     = (bf16_t*)w;
  bf16_t* xconv   = (bf16_t*)(w + OFF_XC);
  float*  dtv     = (float*)(w + OFF_DT);
  float*  acsb    = (float*)(w + OFF_ACS);
  float*  totals  = (float*)(w + OFF_TOT);
  float*  states  = (float*)(w + OFF_ST);
  bf16_t* arena   = (bf16_t*)(w + OFF_AR);
  bf16_t* u_bf    = arena;
  bf16_t* Wpad    = arena + (size_t)ROWS * 1024;
  bf16_t* prevbf  = arena;                      // overlays u_bf (dead)
  bf16_t* ypre_bf = arena;                      // overlays prevbf (dead)
  bf16_t* Wout_bf = arena + (size_t)ROWS * DSSM;
  bf16_t* ypre_ov = zxb + 2048;                 // bf16 overlay: zx cols 2048..4095

  // 0. casts
  {
    const long n_u = (long)ROWS * 1024;
    cast_f32_bf16<<<dim3((n_u/8 + 255)/256), 256, 0, stream>>>(u, u_bf, n_u, n_u);
    const long n_wv = (long)4384 * 1024, n_wt = (long)4480 * 1024;
    cast_f32_bf16<<<dim3((n_wt/8 + 255)/256), 256, 0, stream>>>(W_in, Wpad, n_wv, n_wt);
    const long n_wo = (long)1024 * DSSM;
    cast_f32_bf16<<<dim3((n_wo/8 + 255)/256), 256, 0, stream>>>(W_out, Wout_bf, n_wo, n_wo);
  }
  // 1. in_proj (MFMA bf16 -> bf16 zx)
  gemm_bt_mfma<true><<<dim3(35, 64), 256, 0, stream>>>(u_bf, Wpad, zxb, ROWS, 4384, 1024,
                                                       1024, 1024, ZX_LD);
  // 2. conv + silu -> bf16 xconv
  conv_silu_kernel<<<dim3(9, ROWS), 256, 0, stream>>>(zxb, conv_w, conv_b, xconv);
  // 3. dt softplus
  dt_kernel<<<dim3((ROWS * NH) / 256), 256, 0, stream>>>(zxb, dt_bias, dtv);
  // 4. per-chunk cumsum + states (MFMA)
  chunk_states_kernel<<<dim3(1024), 256, 0, stream>>>(dtv, A_log, xconv, acsb, totals, states);
  // 5. inter-chunk scan -> bf16 prev states
  chunk_prefix_kernel<<<dim3(64, 32), 256, 0, stream>>>(states, totals, prevbf);
  // 6. intra-chunk Y via MFMA -> bf16 overlay in zx
  y_kernel_mfma<<<dim3(4096), 256, 0, stream>>>(xconv, dtv, acsb, prevbf, Dv, ypre_ov, ZX_LD);
  // 7. gated rmsnorm -> bf16 dense
  rmsnorm_gate_kernel<<<dim3(ROWS), 256, 0, stream>>>(zxb, norm_w, ypre_bf);
  // 8. out_proj (MFMA bf16 -> f32 out)
  gemm_bt_mfma<false><<<dim3(8, 64), 256, 0, stream>>>(ypre_bf, Wout_bf, out, ROWS, 1024, 2048,
                                                       2048, 2048, 1024);
}

// Round 9
// 502.686 us; speedup vs baseline: 4.0883x; 1.0112x over previous
//
#include <hip/hip_runtime.h>
#include <hip/hip_bf16.h>

// ---- problem constants ----
#define ZX_LD   4384   // in_proj output width (z 2048 | xBC 2304 | dt 32)
#define XC_LD   2304   // conv dim (x 2048 | B 128 | C 128)
#define NH      32
#define HD      64
#define DS      128
#define CHK     256
#define NC      16
#define LTOT    4096
#define ROWS    8192   // BATCH * SEQLEN
#define DSSM    2048
#define YPAD    80     // Sl/xT row stride (bf16) in y-kernel

typedef __bf16 bf16_t;
typedef bf16_t bf16x8 __attribute__((ext_vector_type(8)));
typedef float  f32x4  __attribute__((ext_vector_type(4)));
typedef unsigned short u16x8 __attribute__((ext_vector_type(8)));

__device__ inline float bf2f(unsigned short u) {
  unsigned int x = ((unsigned int)u) << 16;
  float f; __builtin_memcpy(&f, &x, 4); return f;
}

#define GLOAD_LDS16(gp, lp) \
  __builtin_amdgcn_global_load_lds((const __attribute__((address_space(1))) void*)(gp), \
                                   (__attribute__((address_space(3))) void*)(lp), 16, 0, 0)

// =====================================================================
// cast fp32 -> bf16, zero-fill past nvalid (nvalid multiple of 8)
// =====================================================================
__global__ __launch_bounds__(256) void cast_f32_bf16(
    const float* __restrict__ in, bf16_t* __restrict__ out,
    long nvalid, long total)
{
  const long e0 = ((long)blockIdx.x * 256 + threadIdx.x) * 8;
  if (e0 >= total) return;
  bf16x8 o;
  if (e0 + 8 <= nvalid) {
    const float4 a = *(const float4*)(in + e0);
    const float4 b = *(const float4*)(in + e0 + 4);
    o[0]=(bf16_t)a.x; o[1]=(bf16_t)a.y; o[2]=(bf16_t)a.z; o[3]=(bf16_t)a.w;
    o[4]=(bf16_t)b.x; o[5]=(bf16_t)b.y; o[6]=(bf16_t)b.z; o[7]=(bf16_t)b.w;
  } else {
#pragma unroll
    for (int j = 0; j < 8; ++j) o[j] = (bf16_t)0.f;
  }
  *(bf16x8*)(out + e0) = o;
}

// =====================================================================
// bf16 MFMA GEMM: C[m][n] = sum_k A[m][k]*B[n][k]  (m97-style 2-barrier)
// + XCD-bijective blockIdx swizzle (T1). BF16OUT selects C dtype.
// =====================================================================
template<bool BF16OUT>
__global__ __launch_bounds__(256) void gemm_bt_mfma(
    const bf16_t* __restrict__ A, const bf16_t* __restrict__ B,
    void* __restrict__ Cv, int M, int N, int K,
    int lda, int ldb, int ldc)
{
  __shared__ __align__(16) bf16_t As[128 * 32];
  __shared__ __align__(16) bf16_t Bs[128 * 32];
  const int tid  = threadIdx.x;
  const int lane = tid & 63;
  const int wave = tid >> 6;

  // XCD-aware bijective swizzle of the flattened workgroup id
  const int nwg  = gridDim.x * gridDim.y;
  int wgid = blockIdx.y * gridDim.x + blockIdx.x;
  {
    const int xcd = wgid & 7, local = wgid >> 3;
    const int q = nwg >> 3, r = nwg & 7;
    wgid = (xcd < r ? xcd * (q + 1) : r * (q + 1) + (xcd - r) * q) + local;
  }
  const int bm = (wgid / gridDim.x) * 128;
  const int bn = (wgid % gridDim.x) * 128;

  const int wr = (wave >> 1) * 64;
  const int wc = (wave & 1) * 64;

  const int c0   = wave * 2;
  const int lrow = lane >> 2;
  const int lcol = (lane & 3) * 8;
  const bf16_t* Ag0 = A + (size_t)(bm + c0 * 16 + lrow) * lda + lcol;
  const bf16_t* Ag1 = A + (size_t)(bm + c0 * 16 + 16 + lrow) * lda + lcol;
  const bf16_t* Bg0 = B + (size_t)(bn + c0 * 16 + lrow) * ldb + lcol;
  const bf16_t* Bg1 = B + (size_t)(bn + c0 * 16 + 16 + lrow) * ldb + lcol;
  bf16_t* Al0 = As + c0 * 512;
  bf16_t* Al1 = As + c0 * 512 + 512;
  bf16_t* Bl0 = Bs + c0 * 512;
  bf16_t* Bl1 = Bs + c0 * 512 + 512;

  f32x4 acc[4][4];
#pragma unroll
  for (int i = 0; i < 4; ++i)
#pragma unroll
    for (int j = 0; j < 4; ++j) acc[i][j] = (f32x4){0.f, 0.f, 0.f, 0.f};

  const int nk = K >> 5;
  for (int kt = 0; kt < nk; ++kt) {
    const int k0 = kt * 32;
    __syncthreads();
    GLOAD_LDS16(Ag0 + k0, Al0);
    GLOAD_LDS16(Ag1 + k0, Al1);
    GLOAD_LDS16(Bg0 + k0, Bl0);
    GLOAD_LDS16(Bg1 + k0, Bl1);
    __syncthreads();

    const bf16_t* Ab = As + (wr + (lane & 15)) * 32 + (lane >> 4) * 8;
    const bf16_t* Bb = Bs + (wc + (lane & 15)) * 32 + (lane >> 4) * 8;
    bf16x8 af[4], bfv[4];
#pragma unroll
    for (int mi = 0; mi < 4; ++mi) af[mi]  = *(const bf16x8*)(Ab + mi * 512);
#pragma unroll
    for (int ni = 0; ni < 4; ++ni) bfv[ni] = *(const bf16x8*)(Bb + ni * 512);
#pragma unroll
    for (int mi = 0; mi < 4; ++mi)
#pragma unroll
      for (int ni = 0; ni < 4; ++ni)
        acc[mi][ni] = __builtin_amdgcn_mfma_f32_16x16x32_bf16(af[mi], bfv[ni], acc[mi][ni], 0, 0, 0);
  }

  const int crow0 = bm + wr + (lane >> 4) * 4;
  const int ccol0 = bn + wc + (lane & 15);
#pragma unroll
  for (int ni = 0; ni < 4; ++ni) {
    const int ccol = ccol0 + ni * 16;
    if (ccol < N) {
#pragma unroll
      for (int mi = 0; mi < 4; ++mi) {
#pragma unroll
        for (int j = 0; j < 4; ++j) {
          if constexpr (BF16OUT) {
            ((bf16_t*)Cv)[(size_t)(crow0 + mi * 16 + j) * ldc + ccol] = (bf16_t)acc[mi][ni][j];
          } else {
            ((float*)Cv)[(size_t)(crow0 + mi * 16 + j) * ldc + ccol] = acc[mi][ni][j];
          }
        }
      }
    }
  }
}

// =====================================================================
// depthwise causal conv (k=4) + bias + SiLU; bf16 zx -> bf16 xconv
// =====================================================================
__global__ __launch_bounds__(256) void conv_silu_kernel(
    const bf16_t* __restrict__ zx, const float* __restrict__ cw,
    const float* __restrict__ cb, bf16_t* __restrict__ xconv)
{
  const int ch  = blockIdx.x * 256 + threadIdx.x;  // 0..2303
  const int row = blockIdx.y;                      // 0..8191
  const int l   = row & (LTOT - 1);
  float acc = cb[ch];
#pragma unroll
  for (int k = 0; k < 4; ++k) {
    const int ls = l - 3 + k;
    if (ls >= 0)
      acc = fmaf((float)zx[(size_t)(row - 3 + k) * ZX_LD + 2048 + ch], cw[ch*4 + k], acc);
  }
  const float r = acc / (1.f + __expf(-acc));   // silu
  xconv[(size_t)row * XC_LD + ch] = (bf16_t)r;
}

// =====================================================================
// dt = softplus(dt_raw + dt_bias)
// =====================================================================
__global__ __launch_bounds__(256) void dt_kernel(
    const bf16_t* __restrict__ zx, const float* __restrict__ dtb,
    float* __restrict__ dtv)
{
  const int idx = blockIdx.x * 256 + threadIdx.x;  // < ROWS*NH
  const int row = idx >> 5;
  const int hh  = idx & 31;
  const float x = (float)zx[(size_t)row * ZX_LD + 4352 + hh] + dtb[hh];
  dtv[idx] = (x > 20.f) ? x : log1pf(__expf(x));
}

// =====================================================================
// per (b,c,h): cumsum(dA); chunk totals; chunk states via MFMA.
// + XCD-chunked bid swizzle (blocks of same (b,c) share B in L2)
// =====================================================================
__global__ __launch_bounds__(256) void chunk_states_kernel(
    const float* __restrict__ dtv, const float* __restrict__ A_log,
    const bf16_t* __restrict__ xconv,
    float* __restrict__ acs, float* __restrict__ totals,
    float* __restrict__ states)
{
  const int bid0 = blockIdx.x;
  const int bid  = (bid0 & 7) * 128 + (bid0 >> 3);   // 1024 blocks, chunked per XCD
  const int h = bid & 31;
  const int c = (bid >> 5) & 15;
  const int b = bid >> 9;
  const int rowbase = b * LTOT + c * CHK;
  const int tid = threadIdx.x;
  const int lane = tid & 63;
  const int wv   = tid >> 6;
  const int ln15 = lane & 15;
  const int lg   = lane >> 4;

  __shared__ float sWdt[256];
  __shared__ float wsum[4];
  __shared__ __align__(16) bf16_t xT[64 * 64];    // [p][l] swizzled
  __shared__ __align__(16) bf16_t Bt[128 * 64];   // [n][l] swizzled
  unsigned short* Btu = (unsigned short*)Bt;

  const float dt = dtv[(size_t)(rowbase + tid) * NH + h];
  const float Ah = -__expf(A_log[h]);
  float v = dt * Ah;
#pragma unroll
  for (int off = 1; off < 64; off <<= 1) {
    float up = __shfl_up(v, off, 64);
    if ((tid & 63) >= off) v += up;
  }
  if ((tid & 63) == 63) wsum[tid >> 6] = v;
  __syncthreads();
  const float w0 = wsum[0], w1 = wsum[1], w2 = wsum[2], w3 = wsum[3];
  float base = 0.f;
  if (wv > 0) base += w0;
  if (wv > 1) base += w1;
  if (wv > 2) base += w2;
  const float acsl  = v + base;
  const float total = w0 + w1 + w2 + w3;
  acs[bid * 256 + tid] = acsl;
  if (tid == 0) totals[(b * 32 + h) * 16 + c] = total;
  sWdt[tid] = __expf(total - acsl) * dt;

  f32x4 acc[4][2];
#pragma unroll
  for (int i = 0; i < 4; ++i)
#pragma unroll
    for (int j = 0; j < 2; ++j) acc[i][j] = (f32x4){0.f, 0.f, 0.f, 0.f};

  const int s  = tid >> 2;
  const int p0 = (tid & 3) * 16;
  const int n0 = (tid & 3) * 32;

  for (int ls = 0; ls < 4; ++ls) {
    const int l0 = ls * 64;
    __syncthreads();
    {
      const float wgt = sWdt[l0 + s];
      const bf16_t* xr = xconv + (size_t)(rowbase + l0 + s) * XC_LD + h * HD + p0;
      u16x8 v0 = *(const u16x8*)xr;
      u16x8 v1 = *(const u16x8*)(xr + 8);
#pragma unroll
      for (int j = 0; j < 8; ++j) {
        const int p = p0 + j;
        xT[p * 64 + ((((s >> 3) ^ (p & 7)) << 3) | (s & 7))] = (bf16_t)(bf2f(v0[j]) * wgt);
      }
#pragma unroll
      for (int j = 0; j < 8; ++j) {
        const int p = p0 + 8 + j;
        xT[p * 64 + ((((s >> 3) ^ (p & 7)) << 3) | (s & 7))] = (bf16_t)(bf2f(v1[j]) * wgt);
      }
      const bf16_t* br = xconv + (size_t)(rowbase + l0 + s) * XC_LD + 2048 + n0;
#pragma unroll
      for (int q = 0; q < 4; ++q) {
        u16x8 t = *(const u16x8*)(br + q * 8);
#pragma unroll
        for (int j = 0; j < 8; ++j) {
          const int n = n0 + q * 8 + j;
          Btu[n * 64 + ((((s >> 3) ^ (n & 7)) << 3) | (s & 7))] = t[j];
        }
      }
    }
    __syncthreads();
#pragma unroll
    for (int ks = 0; ks < 2; ++ks) {
      bf16x8 af[4];
#pragma unroll
      for (int mi = 0; mi < 4; ++mi) {
        const int row = mi * 16 + ln15;
        const int chunk = (ks * 4 + lg) ^ (row & 7);
        af[mi] = *(const bf16x8*)(xT + row * 64 + chunk * 8);
      }
#pragma unroll
      for (int ni = 0; ni < 2; ++ni) {
        const int nrow = wv * 32 + ni * 16 + ln15;
        const int chunk = (ks * 4 + lg) ^ (nrow & 7);
        bf16x8 bfr = *(const bf16x8*)(Bt + nrow * 64 + chunk * 8);
#pragma unroll
        for (int mi = 0; mi < 4; ++mi)
          acc[mi][ni] = __builtin_amdgcn_mfma_f32_16x16x32_bf16(af[mi], bfr, acc[mi][ni], 0, 0, 0);
      }
    }
  }

  const size_t sbase = (size_t)bid * (HD * DS);
#pragma unroll
  for (int mi = 0; mi < 4; ++mi) {
#pragma unroll
    for (int ni = 0; ni < 2; ++ni) {
      const int n = wv * 32 + ni * 16 + ln15;
#pragma unroll
      for (int j = 0; j < 4; ++j) {
        const int p = mi * 16 + lg * 4 + j;
        states[sbase + p * DS + n] = acc[mi][ni][j];
      }
    }
  }
}

// =====================================================================
// inter-chunk scan: grid (64 bh, 32 e-groups); prev-state -> bf16 prevbf
// =====================================================================
__global__ __launch_bounds__(256) void chunk_prefix_kernel(
    const float* __restrict__ st, const float* __restrict__ totals,
    bf16_t* __restrict__ prevbf)
{
  const int bh = blockIdx.x;   // b*32+h
  const int b = bh >> 5;
  const int h = bh & 31;
  const int e = blockIdx.y;    // 0..31
  const int tid = threadIdx.x;
  float P = 0.f;
  for (int c = 0; c < NC; ++c) {
    const size_t idx = (size_t)((b * 16 + c) * 32 + h) * (HD * DS) + e * 256 + tid;
    const float g = __expf(totals[bh * 16 + c]);
    prevbf[idx] = (bf16_t)P;
    P = fmaf(P, g, st[idx]);
  }
}

// =====================================================================
// Y kernel, MFMA + XCD-chunked swizzle + register-prefetch pipeline.
// Block = (b,c,h,lt); lt-quads land on one XCD (x/B/C reuse in L2).
// st-loop consumes B-frags/x-rows prefetched the previous iteration.
// =====================================================================
__global__ __launch_bounds__(256) void y_kernel_mfma(
    const bf16_t* __restrict__ xconv, const float* __restrict__ dtv,
    const float* __restrict__ acs,   const bf16_t* __restrict__ prevbf,
    const float* __restrict__ Dv,    bf16_t* __restrict__ ypre, int ypld)
{
  const int bid0 = blockIdx.x;
  const int bid  = (bid0 & 7) * 512 + (bid0 >> 3);   // 4096 blocks, chunked per XCD
  const int lt = bid & 3;
  const int h  = (bid >> 2) & 31;
  const int c  = (bid >> 7) & 15;
  const int b  = bid >> 11;
  const int bch = (b * 16 + c) * 32 + h;
  const int rowbase = b * LTOT + c * CHK;
  const int tid  = threadIdx.x;
  const int lane = tid & 63;
  const int wv   = tid >> 6;
  const int ln15 = lane & 15;
  const int lg   = lane >> 4;

  __shared__ float sAcs[256];
  __shared__ float sDt[256];
  __shared__ __align__(16) bf16_t Sl[64 * YPAD];
  __shared__ __align__(16) bf16_t xT[64 * YPAD];
  unsigned short* xTu = (unsigned short*)xT;

  sAcs[tid] = acs[bch * 256 + tid];
  sDt[tid]  = dtv[(size_t)(rowbase + tid) * NH + h];
  __syncthreads();

  // ---- C A-frags direct from global ----
  bf16x8 cf[4][4];
#pragma unroll
  for (int mi = 0; mi < 4; ++mi) {
    const bf16_t* crow = xconv + (size_t)(rowbase + lt*64 + mi*16 + ln15) * XC_LD + 2176 + lg * 8;
#pragma unroll
    for (int ks = 0; ks < 4; ++ks) cf[mi][ks] = *(const bf16x8*)(crow + ks * 32);
  }

  // ---- CP term ----
  f32x4 acc[4];
#pragma unroll
  for (int mi = 0; mi < 4; ++mi) acc[mi] = (f32x4){0.f, 0.f, 0.f, 0.f};
  {
    const bf16_t* pb = prevbf + ((size_t)bch * 64 + 16 * wv + ln15) * 128 + lg * 8;
#pragma unroll
    for (int ks = 0; ks < 4; ++ks) {
      bf16x8 pf = *(const bf16x8*)(pb + ks * 32);
#pragma unroll
      for (int mi = 0; mi < 4; ++mi)
        acc[mi] = __builtin_amdgcn_mfma_f32_16x16x32_bf16(cf[mi][ks], pf, acc[mi], 0, 0, 0);
    }
  }
#pragma unroll
  for (int mi = 0; mi < 4; ++mi) {
#pragma unroll
    for (int j = 0; j < 4; ++j)
      acc[mi][j] *= __expf(sAcs[lt*64 + mi*16 + lg*4 + j]);
  }

  // ---- prefetch st=0: x rows + B-frags into registers ----
  u16x8 xv0, xv1;
  bf16x8 bfp[4];
  {
    const bf16_t* xr = xconv + (size_t)(rowbase + (tid >> 2)) * XC_LD + h * HD + (tid & 3) * 16;
    xv0 = *(const u16x8*)xr;
    xv1 = *(const u16x8*)(xr + 8);
    const bf16_t* brow = xconv + (size_t)(rowbase + 16*wv + ln15) * XC_LD + 2048 + lg * 8;
#pragma unroll
    for (int ks = 0; ks < 4; ++ks) bfp[ks] = *(const bf16x8*)(brow + ks * 32);
  }

  // ---- causal st loop (pipelined) ----
  for (int st = 0; st <= lt; ++st) {
    __syncthreads();   // prior PV done reading Sl/xT
    // write xT from prefetched regs
    {
      const int s  = tid >> 2;
      const int p0 = (tid & 3) * 16;
#pragma unroll
      for (int j = 0; j < 8; ++j) xTu[(p0 + j) * YPAD + s] = xv0[j];
#pragma unroll
      for (int j = 0; j < 8; ++j) xTu[(p0 + 8 + j) * YPAD + s] = xv1[j];
    }

    // QK with prefetched B-frags
    f32x4 sa[4];
#pragma unroll
    for (int mi = 0; mi < 4; ++mi) sa[mi] = (f32x4){0.f, 0.f, 0.f, 0.f};
#pragma unroll
    for (int ks = 0; ks < 4; ++ks) {
#pragma unroll
      for (int mi = 0; mi < 4; ++mi)
        sa[mi] = __builtin_amdgcn_mfma_f32_16x16x32_bf16(cf[mi][ks], bfp[ks], sa[mi], 0, 0, 0);
    }

    // prefetch st+1 (latency hidden under decay+barrier+PV)
    if (st < lt) {
      const bf16_t* xr = xconv + (size_t)(rowbase + (st+1)*64 + (tid >> 2)) * XC_LD + h * HD + (tid & 3) * 16;
      xv0 = *(const u16x8*)xr;
      xv1 = *(const u16x8*)(xr + 8);
      const bf16_t* brow = xconv + (size_t)(rowbase + (st+1)*64 + 16*wv + ln15) * XC_LD + 2048 + lg * 8;
#pragma unroll
      for (int ks = 0; ks < 4; ++ks) bfp[ks] = *(const bf16x8*)(brow + ks * 32);
    }

    // decay * mask * dt -> bf16 -> Sl[l][s]
    {
      const int sg = st * 64 + 16 * wv + ln15;
      const float as  = sAcs[sg];
      const float dts = sDt[sg];
#pragma unroll
      for (int mi = 0; mi < 4; ++mi) {
#pragma unroll
        for (int j = 0; j < 4; ++j) {
          const int lloc = mi * 16 + lg * 4 + j;
          const int ll = lt * 64 + lloc;
          float wvv = 0.f;
          if (ll >= sg) wvv = sa[mi][j] * __expf(sAcs[ll] - as) * dts;
          Sl[lloc * YPAD + 16 * wv + ln15] = (bf16_t)wvv;
        }
      }
    }
    __syncthreads();   // Sl/xT visible

    // PV: acc += S~ @ x
#pragma unroll
    for (int ks2 = 0; ks2 < 2; ++ks2) {
      bf16x8 xf = *(const bf16x8*)(xT + (16 * wv + ln15) * YPAD + ks2 * 32 + lg * 8);
#pragma unroll
      for (int mi = 0; mi < 4; ++mi) {
        bf16x8 sf = *(const bf16x8*)(Sl + (mi * 16 + ln15) * YPAD + ks2 * 32 + lg * 8);
        acc[mi] = __builtin_amdgcn_mfma_f32_16x16x32_bf16(sf, xf, acc[mi], 0, 0, 0);
      }
    }
  }

  // ---- epilogue: + x*D (xT holds st=lt rows), write bf16 ----
  const float Dh = Dv[h];
  const int p = 16 * wv + ln15;
#pragma unroll
  for (int mi = 0; mi < 4; ++mi) {
#pragma unroll
    for (int j = 0; j < 4; ++j) {
      const int lloc = mi * 16 + lg * 4 + j;
      const int row  = rowbase + lt * 64 + lloc;
      const float xv = (float)xT[p * YPAD + lloc];
      ypre[(size_t)row * ypld + h * HD + p] = (bf16_t)(acc[mi][j] + xv * Dh);
    }
  }
}

// =====================================================================
// gated RMSNorm: z and y both bf16 in zx; write bf16 ypre_bf (dense)
// =====================================================================
__global__ __launch_bounds__(256) void rmsnorm_gate_kernel(
    const bf16_t* __restrict__ zx, const float* __restrict__ normw,
    bf16_t* __restrict__ ypre_bf)
{
  const int row = blockIdx.x;
  const int tid = threadIdx.x;
  const unsigned short* zr = (const unsigned short*)(zx + (size_t)row * ZX_LD);
  u16x8 yv = *(const u16x8*)(zr + 2048 + tid * 8);
  u16x8 zv = *(const u16x8*)(zr + tid * 8);
  float vals[8];
  float ss = 0.f;
#pragma unroll
  for (int j = 0; j < 8; ++j) {
    const float y = bf2f(yv[j]);
    const float z = bf2f(zv[j]);
    const float sz = z / (1.f + __expf(-z));
    const float v = y * sz;
    vals[j] = v;
    ss += v * v;
  }
#pragma unroll
  for (int off = 32; off >= 1; off >>= 1) ss += __shfl_xor(ss, off, 64);
  __shared__ float red[4];
  if ((tid & 63) == 0) red[tid >> 6] = ss;
  __syncthreads();
  const float tot = red[0] + red[1] + red[2] + red[3];
  const float scale = rsqrtf(tot / (float)DSSM + 1e-5f);
  const float4 w0 = *(const float4*)(normw + tid * 8);
  const float4 w1 = *(const float4*)(normw + tid * 8 + 4);
  bf16x8 o;
  o[0] = (bf16_t)(vals[0] * scale * w0.x);
  o[1] = (bf16_t)(vals[1] * scale * w0.y);
  o[2] = (bf16_t)(vals[2] * scale * w0.z);
  o[3] = (bf16_t)(vals[3] * scale * w0.w);
  o[4] = (bf16_t)(vals[4] * scale * w1.x);
  o[5] = (bf16_t)(vals[5] * scale * w1.y);
  o[6] = (bf16_t)(vals[6] * scale * w1.z);
  o[7] = (bf16_t)(vals[7] * scale * w1.w);
  *(bf16x8*)(ypre_bf + (size_t)row * DSSM + tid * 8) = o;
}

// =====================================================================
extern "C" void kernel_launch(void* const* d_in, const int* in_sizes, int n_in,
                              void* d_out, int out_size, void* d_ws, size_t ws_size,
                              hipStream_t stream)
{
  const float* u       = (const float*)d_in[0];
  const float* W_in    = (const float*)d_in[1];
  const float* conv_w  = (const float*)d_in[2];
  const float* conv_b  = (const float*)d_in[3];
  const float* dt_bias = (const float*)d_in[4];
  const float* A_log   = (const float*)d_in[5];
  const float* Dv      = (const float*)d_in[6];
  const float* norm_w  = (const float*)d_in[7];
  const float* W_out   = (const float*)d_in[8];
  float* out = (float*)d_out;

  // ---- workspace layout (byte offsets), ~183 MiB total ----
  const size_t OFF_XC  = (size_t)ROWS * ZX_LD * 2;              // zx bf16
  const size_t OFF_DT  = OFF_XC  + (size_t)ROWS * XC_LD * 2;    // xconv bf16
  const size_t OFF_ACS = OFF_DT  + (size_t)ROWS * NH * 4;       // dtv f32
  const size_t OFF_TOT = OFF_ACS + (size_t)1024 * 256 * 4;      // acs f32
  const size_t OFF_ST  = OFF_TOT + 4096;                        // totals
  const size_t OFF_AR  = OFF_ST  + (size_t)1024 * HD * DS * 4;  // states f32
  const size_t need    = OFF_AR  + (size_t)ROWS * XC_LD * 2;    // arena bf16
  if (ws_size < need) return;

  char* w = (char*)d_ws;
  bf16_t* zxb     = (bf16_t*)w;
  bf16_t* xconv   = (bf16_t*)(w + OFF_XC);
  float*  dtv     = (float*)(w + OFF_DT);
  float*  acsb    = (float*)(w + OFF_ACS);
  float*  totals  = (float*)(w + OFF_TOT);
  float*  states  = (float*)(w + OFF_ST);
  bf16_t* arena   = (bf16_t*)(w + OFF_AR);
  bf16_t* u_bf    = arena;
  bf16_t* Wpad    = arena + (size_t)ROWS * 1024;
  bf16_t* prevbf  = arena;                      // overlays u_bf (dead)
  bf16_t* ypre_bf = arena;                      // overlays prevbf (dead)
  bf16_t* Wout_bf = arena + (size_t)ROWS * DSSM;
  bf16_t* ypre_ov = zxb + 2048;                 // bf16 overlay: zx cols 2048..4095

  // 0. casts
  {
    const long n_u = (long)ROWS * 1024;
    cast_f32_bf16<<<dim3((n_u/8 + 255)/256), 256, 0, stream>>>(u, u_bf, n_u, n_u);
    const long n_wv = (long)4384 * 1024, n_wt = (long)4480 * 1024;
    cast_f32_bf16<<<dim3((n_wt/8 + 255)/256), 256, 0, stream>>>(W_in, Wpad, n_wv, n_wt);
    const long n_wo = (long)1024 * DSSM;
    cast_f32_bf16<<<dim3((n_wo/8 + 255)/256), 256, 0, stream>>>(W_out, Wout_bf, n_wo, n_wo);
  }
  // 1. in_proj (MFMA bf16 -> bf16 zx)
  gemm_bt_mfma<true><<<dim3(35, 64), 256, 0, stream>>>(u_bf, Wpad, zxb, ROWS, 4384, 1024,
                                                       1024, 1024, ZX_LD);
  // 2. conv + silu -> bf16 xconv
  conv_silu_kernel<<<dim3(9, ROWS), 256, 0, stream>>>(zxb, conv_w, conv_b, xconv);
  // 3. dt softplus
  dt_kernel<<<dim3((ROWS * NH) / 256), 256, 0, stream>>>(zxb, dt_bias, dtv);
  // 4. per-chunk cumsum + states (MFMA, XCD-chunked)
  chunk_states_kernel<<<dim3(1024), 256, 0, stream>>>(dtv, A_log, xconv, acsb, totals, states);
  // 5. inter-chunk scan -> bf16 prev states
  chunk_prefix_kernel<<<dim3(64, 32), 256, 0, stream>>>(states, totals, prevbf);
  // 6. intra-chunk Y via MFMA (XCD-chunked, pipelined) -> bf16 overlay in zx
  y_kernel_mfma<<<dim3(4096), 256, 0, stream>>>(xconv, dtv, acsb, prevbf, Dv, ypre_ov, ZX_LD);
  // 7. gated rmsnorm -> bf16 dense
  rmsnorm_gate_kernel<<<dim3(ROWS), 256, 0, stream>>>(zxb, norm_w, ypre_bf);
  // 8. out_proj (MFMA bf16 -> f32 out)
  gemm_bt_mfma<false><<<dim3(8, 64), 256, 0, stream>>>(ypre_bf, Wout_bf, out, ROWS, 1024, 2048,
                                                       2048, 2048, 1024);
}